// Round 15
// baseline (332.783 us; speedup 1.0000x reference)
//
#include <hip/hip_runtime.h>

#define NN 50000
#define EE 600000
#define FF 128
#define HH 8
#define CC 16
#define DD 128
#define EPAD 950272   // >= EE + 7*NN + 24 sentinels
#define NBLK 196      // ceil(NN/256)

typedef unsigned short u16;
typedef _Float16 h2t __attribute__((ext_vector_type(2)));
typedef _Float16 h8 __attribute__((ext_vector_type(8)));
typedef float f4 __attribute__((ext_vector_type(4)));

#if defined(__has_builtin)
#if __has_builtin(__builtin_amdgcn_fdot2)
#define HAS_FDOT2 1
#endif
#endif

static __device__ __forceinline__ float h2f(u16 u) {
    _Float16 h; __builtin_memcpy(&h, &u, 2); return (float)h;
}
static __device__ __forceinline__ u16 f2h(float f) {
    _Float16 h = (_Float16)f; u16 u; __builtin_memcpy(&u, &h, 2); return u;
}
static __device__ __forceinline__ float lo2f(unsigned x) { return h2f((u16)(x & 0xffff)); }
static __device__ __forceinline__ float hi2f(unsigned x) { return h2f((u16)(x >> 16)); }

static __device__ __forceinline__ float dot8(uint4 a, uint4 b, float c) {
#ifdef HAS_FDOT2
    h2t ax[4], bx[4];
    __builtin_memcpy(&ax, &a, 16); __builtin_memcpy(&bx, &b, 16);
    c = __builtin_amdgcn_fdot2(ax[0], bx[0], c, false);
    c = __builtin_amdgcn_fdot2(ax[1], bx[1], c, false);
    c = __builtin_amdgcn_fdot2(ax[2], bx[2], c, false);
    c = __builtin_amdgcn_fdot2(ax[3], bx[3], c, false);
#else
    c += lo2f(a.x) * lo2f(b.x) + hi2f(a.x) * hi2f(b.x)
       + lo2f(a.y) * lo2f(b.y) + hi2f(a.y) * hi2f(b.y)
       + lo2f(a.z) * lo2f(b.z) + hi2f(a.z) * hi2f(b.z)
       + lo2f(a.w) * lo2f(b.w) + hi2f(a.w) * hi2f(b.w);
#endif
    return c;
}
static __device__ __forceinline__ float dot8h(uint4 a, const h2t* pk, float c) {
#ifdef HAS_FDOT2
    h2t ax[4];
    __builtin_memcpy(&ax, &a, 16);
    c = __builtin_amdgcn_fdot2(ax[0], pk[0], c, false);
    c = __builtin_amdgcn_fdot2(ax[1], pk[1], c, false);
    c = __builtin_amdgcn_fdot2(ax[2], pk[2], c, false);
    c = __builtin_amdgcn_fdot2(ax[3], pk[3], c, false);
#else
    c += lo2f(a.x) * (float)pk[0][0] + hi2f(a.x) * (float)pk[0][1]
       + lo2f(a.y) * (float)pk[1][0] + hi2f(a.y) * (float)pk[1][1]
       + lo2f(a.z) * (float)pk[2][0] + hi2f(a.z) * (float)pk[2][1]
       + lo2f(a.w) * (float)pk[3][0] + hi2f(a.w) * (float)pk[3][1];
#endif
    return c;
}

// LDS tile swizzle: tile is [128 rows][128 f16]; 16B-unit index with XOR
static __device__ __forceinline__ int tswz(int row, int u) {
    return (row * 16 + (u ^ (row & 7))) * 8;   // u16 element index
}

// ---------------------------------------------------------------------------
// MEGA prep kernel: node norms + x->f16 | weight cvt | precompute | histogram
// ---------------------------------------------------------------------------
#define NBP 12500
__global__ void k_prep(const float* __restrict__ x, float* __restrict__ norms,
                       u16* __restrict__ xb,
                       const float* __restrict__ s0, u16* __restrict__ d0,
                       const float* __restrict__ s1, u16* __restrict__ d1,
                       const float* __restrict__ s2, u16* __restrict__ d2,
                       const float* __restrict__ s3, u16* __restrict__ d3,
                       const float* __restrict__ lew1, const float* __restrict__ aew1,
                       const float* __restrict__ lew2, const float* __restrict__ aew2,
                       const float* __restrict__ enc_w2, const float* __restrict__ enc_b2,
                       float* __restrict__ P1, float* __restrict__ q1,
                       float* __restrict__ P2, float* __restrict__ q2,
                       const int* __restrict__ ei, int* __restrict__ deg) {
    __shared__ float sM1[64], sM2[64];
    int bb = blockIdx.x;
    int t = threadIdx.x;
    if (bb < NBP) {
        int wid = t >> 6, lane = t & 63;
        int row = bb * 4 + wid;
        float2 v = ((const float2*)(x + (size_t)row * FF))[lane];
        float s = v.x * v.x + v.y * v.y;
        #pragma unroll
        for (int off = 1; off < 64; off <<= 1) s += __shfl_xor(s, off, 64);
        if (lane == 0) norms[row] = s;
        unsigned pk = (unsigned)f2h(v.x) | ((unsigned)f2h(v.y) << 16);
        *(unsigned*)(xb + (size_t)row * FF + lane * 2) = pk;
    } else if (bb < NBP + 48) {
        int b = bb - NBP;
        const float* s; u16* d; int base;
        if (b < 8)       { s = s0; d = d0; base = b * 2048; }
        else if (b < 16) { s = s1; d = d1; base = (b - 8) * 2048; }
        else if (b < 24) { s = s2; d = d2; base = (b - 16) * 2048; }
        else             { s = s3; d = d3; base = (b - 24) * 2048; }
        int i = base + t * 8;
        float4 v0 = *(const float4*)(s + i);
        float4 v1 = *(const float4*)(s + i + 4);
        u16 o[8] = {f2h(v0.x), f2h(v0.y), f2h(v0.z), f2h(v0.w),
                    f2h(v1.x), f2h(v1.y), f2h(v1.z), f2h(v1.w)};
        *(uint4*)(d + i) = *(uint4*)o;
    } else if (bb == NBP + 48) {
        if (t < 128) {
            int kk = (t & 63) >> 3, h = t & 7;
            const float* lew = (t < 64) ? lew1 : lew2;
            const float* ae  = (t < 64) ? aew1 : aew2;
            float s = 0.f;
            for (int c = 0; c < 16; ++c) s += lew[(h * 16 + c) * 8 + kk] * ae[h * 16 + c];
            if (t < 64) sM1[kk * 8 + h] = s; else sM2[kk * 8 + h] = s;
        }
        __syncthreads();
        if (t < 128) {
            int c = t >> 3, h = t & 7;
            float p1 = 0.f, p2 = 0.f;
            for (int k = 0; k < 8; ++k) {
                float w = enc_w2[k * 16 + c];
                p1 += w * sM1[k * 8 + h];
                p2 += w * sM2[k * 8 + h];
            }
            P1[c * 8 + h] = p1;
            P2[c * 8 + h] = p2;
            if (t < 8) {
                float x1 = 0.f, x2 = 0.f;
                for (int k = 0; k < 8; ++k) { float b = enc_b2[k]; x1 += b * sM1[k * 8 + t]; x2 += b * sM2[k * 8 + t]; }
                q1[t] = x1; q2[t] = x2;
            }
        }
    } else {
        int e = (bb - NBP - 49) * 256 + t;
        if (e < EE) atomicAdd(&deg[ei[EE + e]], 1);
    }
}

// ---------------------------------------------------------------------------
// 3-phase multi-block exclusive scan of padded degrees
// ---------------------------------------------------------------------------
__global__ void k_scan1(const int* __restrict__ deg, int* __restrict__ bsum) {
    int t = threadIdx.x, wid = t >> 6, lane = t & 63;
    int i = blockIdx.x * 256 + t;
    int v = (i < NN) ? ((deg[i] + 7) & ~7) : 0;
    #pragma unroll
    for (int off = 1; off < 64; off <<= 1) v += __shfl_xor(v, off, 64);
    __shared__ int ws[4];
    if (lane == 0) ws[wid] = v;
    __syncthreads();
    if (t == 0) bsum[blockIdx.x] = ws[0] + ws[1] + ws[2] + ws[3];
}

__global__ void k_scan2(int* __restrict__ bsum, int* __restrict__ rp) {
    int t = threadIdx.x, wid = t >> 6, lane = t & 63;
    int v = (t < NBLK) ? bsum[t] : 0;
    int sc = v;
    #pragma unroll
    for (int off = 1; off < 64; off <<= 1) { int n = __shfl_up(sc, off, 64); if (lane >= off) sc += n; }
    __shared__ int ws[4], wso[4];
    if (lane == 63) ws[wid] = sc;
    __syncthreads();
    if (t == 0) {
        int c = 0;
        for (int k = 0; k < 4; ++k) { wso[k] = c; c += ws[k]; }
        rp[NN] = c;
    }
    __syncthreads();
    if (t < NBLK) bsum[t] = sc - v + wso[wid];
}

__global__ void k_scan3(const int* __restrict__ deg, const int* __restrict__ bsum,
                        int* __restrict__ rp, int* __restrict__ cursor) {
    int t = threadIdx.x, wid = t >> 6, lane = t & 63;
    int i = blockIdx.x * 256 + t;
    int v = (i < NN) ? ((deg[i] + 7) & ~7) : 0;
    int sc = v;
    #pragma unroll
    for (int off = 1; off < 64; off <<= 1) { int n = __shfl_up(sc, off, 64); if (lane >= off) sc += n; }
    __shared__ int ws[4], wso[4];
    if (lane == 63) ws[wid] = sc;
    __syncthreads();
    if (t == 0) {
        int c = 0;
        for (int k = 0; k < 4; ++k) { wso[k] = c; c += ws[k]; }
    }
    __syncthreads();
    int ex = bsum[blockIdx.x] + wso[wid] + sc - v;
    if (i < NN) { rp[i] = ex; cursor[i] = ex; }
}

// ---------------------------------------------------------------------------
// scatter (real edges) + fill (padding + sentinels + sentinel-ae zero)
// ---------------------------------------------------------------------------
#define SCB 2344   // ceil(EE/256)
__global__ void k_scatter(const int* __restrict__ ei, int* __restrict__ cursor,
                          const int* __restrict__ deg, const int* __restrict__ rp,
                          int* __restrict__ srt_src, int* __restrict__ srt_dst,
                          u16* __restrict__ ae1, u16* __restrict__ ae2) {
    int bb = blockIdx.x;
    if (bb < SCB) {
        int e = bb * 256 + threadIdx.x;
        if (e < EE) {
            int d = ei[EE + e];
            int pos = atomicAdd(&cursor[d], 1);
            srt_src[pos] = ei[e];
            srt_dst[pos] = d;
        }
    } else {
        int i = (bb - SCB) * 256 + threadIdx.x;
        if (i < NN) {
            int start = rp[i] + deg[i], end = rp[i + 1];
            for (int p = start; p < end; ++p) { srt_src[p] = i; srt_dst[p] = -1; }
        }
        if (i == 0) {
            int ep = rp[NN];
            for (int k = 0; k < 24; ++k) { srt_src[ep + k] = 0; srt_dst[ep + k] = -1; }
            for (int k = 0; k < 192; ++k) { ae1[(size_t)ep * 8 + k] = 0; ae2[(size_t)ep * 8 + k] = 0; }
        }
    }
}

// ---------------------------------------------------------------------------
// K2: edge encoder. 16 lanes/edge, 4 edges/thread. f16 hid exchange in
// unpadded [16][16] LDS, P as f16 pairs via fdot2. Pad edges skip gathers.
// ---------------------------------------------------------------------------
__global__ void k_encoder(const u16* __restrict__ xb,
                          const int* __restrict__ srt_src, const int* __restrict__ srt_dst,
                          const float* __restrict__ norms,
                          const float* __restrict__ enc_w1, const float* __restrict__ enc_b1,
                          const float* __restrict__ P1, const float* __restrict__ q1,
                          const float* __restrict__ P2, const float* __restrict__ q2,
                          u16* __restrict__ ae1out, u16* __restrict__ ae2out,
                          const int* __restrict__ epad) {
    __shared__ __align__(16) u16 hidbuf[16][16];
    int t = threadIdx.x, eq = t >> 4, l = t & 15;
    int conv = l >> 3, h = l & 7;
    int EP = *epad;
    float w0 = enc_w1[l * 4 + 0], w1 = enc_w1[l * 4 + 1];
    float w2 = enc_w1[l * 4 + 2], w3 = enc_w1[l * 4 + 3];
    float cA = w0 - 2.f * w1, cB = w1 + w2, cC = w1 + w3, cb = enc_b1[l];
    const float* Ps = conv ? P2 : P1;
    h2t pk[8];
    #pragma unroll
    for (int c = 0; c < 8; ++c)
        pk[c] = (h2t){(_Float16)Ps[(2 * c) * 8 + h], (_Float16)Ps[(2 * c + 1) * 8 + h]};
    float qreg = conv ? q2[h] : q1[h];
    u16* outp = conv ? ae2out : ae1out;
    int e0 = blockIdx.x * 64 + eq;
    int ss[4], dc[4]; bool ok[4], inr[4];
    #pragma unroll
    for (int j = 0; j < 4; ++j) {
        int e = e0 + j * 16;
        inr[j] = e < EP;
        int eidx = inr[j] ? e : 0;
        int d_ = srt_dst[eidx];
        ss[j] = srt_src[eidx];
        ok[j] = inr[j] && (d_ >= 0);
        dc[j] = d_ >= 0 ? d_ : ss[j];
    }
    uint4 av[4], bv[4];
    float ni[4], nj[4];
    #pragma unroll
    for (int j = 0; j < 4; ++j) {
        if (ok[j]) {
            av[j] = *(const uint4*)(xb + (size_t)ss[j] * FF + l * 8);
            bv[j] = *(const uint4*)(xb + (size_t)dc[j] * FF + l * 8);
            ni[j] = norms[ss[j]]; nj[j] = norms[dc[j]];
        }
    }
    #pragma unroll
    for (int j = 0; j < 4; ++j) {
        if (!inr[j]) continue;
        int e = e0 + j * 16;
        if (!ok[j]) { outp[(size_t)e * 8 + h] = 0; continue; }
        float dot = dot8(av[j], bv[j], 0.f);
        #pragma unroll
        for (int off = 1; off < 16; off <<= 1) dot += __shfl_xor(dot, off, 64);
        float v = cA * dot + cB * ni[j] + cC * nj[j] + cb;
        hidbuf[eq][l] = f2h(v > 0.f ? v : 0.f);
        uint4 h0v = *(const uint4*)&hidbuf[eq][0];
        uint4 h1v = *(const uint4*)&hidbuf[eq][8];
        float a = dot8h(h0v, pk, qreg);
        a = dot8h(h1v, pk + 4, a);
        outp[(size_t)e * 8 + h] = f2h(a);
    }
}

// ---------------------------------------------------------------------------
// K2b: uint4 grid-stride reduction of f16 ae1/ae2 -> sums[16]; one uint4 =
// one edge's 8 heads. Last block computes se1/se2.
// ---------------------------------------------------------------------------
__global__ void k_redsum(const u16* __restrict__ a1, const u16* __restrict__ a2,
                         float* __restrict__ sums, unsigned* __restrict__ done,
                         float* __restrict__ se1, float* __restrict__ se2,
                         const int* __restrict__ epad) {
    int tid = threadIdx.x;  // 256
    int nck = *epad;        // uint4 chunks (one per edge position)
    int gid = blockIdx.x * 256 + tid;
    int stride = gridDim.x * 256;
    float c1[8] = {}, c2[8] = {};
    for (int i = gid; i < nck; i += stride) {
        uint4 v1 = ((const uint4*)a1)[i];
        uint4 v2 = ((const uint4*)a2)[i];
        c1[0] += lo2f(v1.x); c1[1] += hi2f(v1.x); c1[2] += lo2f(v1.y); c1[3] += hi2f(v1.y);
        c1[4] += lo2f(v1.z); c1[5] += hi2f(v1.z); c1[6] += lo2f(v1.w); c1[7] += hi2f(v1.w);
        c2[0] += lo2f(v2.x); c2[1] += hi2f(v2.x); c2[2] += lo2f(v2.y); c2[3] += hi2f(v2.y);
        c2[4] += lo2f(v2.z); c2[5] += hi2f(v2.z); c2[6] += lo2f(v2.w); c2[7] += hi2f(v2.w);
    }
    #pragma unroll
    for (int off = 1; off < 64; off <<= 1) {
        #pragma unroll
        for (int k = 0; k < 8; ++k) {
            c1[k] += __shfl_xor(c1[k], off, 64);
            c2[k] += __shfl_xor(c2[k], off, 64);
        }
    }
    __shared__ float b1[4][8], b2[4][8];
    int wid = tid >> 6, lane = tid & 63;
    if (lane == 0) {
        #pragma unroll
        for (int k = 0; k < 8; ++k) { b1[wid][k] = c1[k]; b2[wid][k] = c2[k]; }
    }
    __syncthreads();
    if (tid < 8) {
        float t1 = b1[0][tid] + b1[1][tid] + b1[2][tid] + b1[3][tid];
        float t2 = b2[0][tid] + b2[1][tid] + b2[2][tid] + b2[3][tid];
        atomicAdd(&sums[tid], t1);
        atomicAdd(&sums[8 + tid], t2);
    }
    __syncthreads();
    if (tid == 0) {
        __threadfence();
        unsigned old = atomicAdd(done, 1u);
        if (old == (unsigned)gridDim.x - 1u) {
            __threadfence();
            for (int hh = 0; hh < 8; ++hh) {
                float v1 = atomicAdd(&sums[hh], 0.f);
                float v2 = atomicAdd(&sums[8 + hh], 0.f);
                se1[hh] = v1 * (1.f / (float)EE);
                se2[hh] = v2 * (1.f / (float)EE);
            }
        }
    }
}

// ---------------------------------------------------------------------------
// att epilogue: per-row per-head dots with att vectors, 16-lane xor reduce
// ---------------------------------------------------------------------------
static __device__ __forceinline__ void att_epilogue(const f4 (&acc)[2][8],
        const float* __restrict__ att_src, const float* __restrict__ att_dst,
        float* __restrict__ a_src, float* __restrict__ a_dst,
        int r0, int w, int lr, int lk, int nrows) {
    float attS[8], attD[8];
    #pragma unroll
    for (int n = 0; n < 8; ++n) { attS[n] = att_src[n * 16 + lr]; attD[n] = att_dst[n * 16 + lr]; }
    int hh = lr & 7;
    #pragma unroll
    for (int m = 0; m < 2; ++m) {
        #pragma unroll
        for (int g = 0; g < 4; ++g) {
            float sv[8], dv[8];
            #pragma unroll
            for (int n = 0; n < 8; ++n) { float p = acc[m][n][g]; sv[n] = p * attS[n]; dv[n] = p * attD[n]; }
            #pragma unroll
            for (int off = 1; off < 16; off <<= 1) {
                #pragma unroll
                for (int n = 0; n < 8; ++n) {
                    sv[n] += __shfl_xor(sv[n], off, 64);
                    dv[n] += __shfl_xor(dv[n], off, 64);
                }
            }
            float so = lr < 8 ? sv[0] : dv[0];
            #pragma unroll
            for (int n = 1; n < 8; ++n) { float c = lr < 8 ? sv[n] : dv[n]; so = (hh == n) ? c : so; }
            int row = r0 + w * 32 + m * 16 + lk * 4 + g;
            if (row < nrows) {
                float* p = lr < 8 ? a_src : a_dst;
                p[(size_t)row * 8 + hh] = so;
            }
        }
    }
}

// ---------------------------------------------------------------------------
// f16 MFMA GEMM (+optional fused att scores)
// ---------------------------------------------------------------------------
template <bool BIAS, bool ATT>
__global__ __launch_bounds__(256, 2) void k_mfma(const u16* __restrict__ X,
                                                 const u16* __restrict__ W,
                                                 const float* __restrict__ bias,
                                                 u16* __restrict__ out,
                                                 const float* __restrict__ att_src,
                                                 const float* __restrict__ att_dst,
                                                 float* __restrict__ a_src,
                                                 float* __restrict__ a_dst, int nrows) {
    __shared__ __align__(16) u16 tA[128 * 128];
    __shared__ __align__(16) u16 tB[128 * 128];
    int t = threadIdx.x;
    int r0 = blockIdx.x * 128;
    #pragma unroll
    for (int it = 0; it < 8; ++it) {
        int idx = it * 256 + t;
        int r = idx >> 4, u = idx & 15;
        uint4 v = make_uint4(0u, 0u, 0u, 0u);
        if (r0 + r < nrows) v = *(const uint4*)(X + (size_t)(r0 + r) * 128 + u * 8);
        *(uint4*)&tA[tswz(r, u)] = v;
        uint4 wv = *(const uint4*)(W + (size_t)r * 128 + u * 8);
        *(uint4*)&tB[tswz(r, u)] = wv;
    }
    __syncthreads();
    int l = t & 63, w = t >> 6;
    int lr = l & 15, lk = l >> 4;
    f4 acc[2][8];
    #pragma unroll
    for (int m = 0; m < 2; ++m)
        #pragma unroll
        for (int n = 0; n < 8; ++n) acc[m][n] = (f4){0.f, 0.f, 0.f, 0.f};
    #pragma unroll
    for (int s = 0; s < 4; ++s) {
        int u = s * 4 + lk;
        h8 a0 = *(h8*)&tA[tswz(w * 32 + lr, u)];
        h8 a1 = *(h8*)&tA[tswz(w * 32 + 16 + lr, u)];
        #pragma unroll
        for (int n = 0; n < 8; ++n) {
            h8 b = *(h8*)&tB[tswz(n * 16 + lr, u)];
            acc[0][n] = __builtin_amdgcn_mfma_f32_16x16x32_f16(a0, b, acc[0][n], 0, 0, 0);
            acc[1][n] = __builtin_amdgcn_mfma_f32_16x16x32_f16(a1, b, acc[1][n], 0, 0, 0);
        }
    }
    #pragma unroll
    for (int n = 0; n < 8; ++n) {
        int col = n * 16 + lr;
        float bv = BIAS ? bias[col] : 0.f;
        #pragma unroll
        for (int m = 0; m < 2; ++m) {
            #pragma unroll
            for (int g = 0; g < 4; ++g) {
                int row = r0 + w * 32 + m * 16 + lk * 4 + g;
                if (row < nrows) out[(size_t)row * 128 + col] = f2h(acc[m][n][g] + bv);
            }
        }
    }
    if (ATT) att_epilogue(acc, att_src, att_dst, a_src, a_dst, r0, w, lr, lk, nrows);
}

// ---------------------------------------------------------------------------
// fused dual GEMM on shared A-tile: out0 = X@W0^T + b0;  out1 = X@W1^T (+att)
// ---------------------------------------------------------------------------
__global__ __launch_bounds__(256, 2) void k_mfma_x2(const u16* __restrict__ X,
                                                    const u16* __restrict__ W0,
                                                    const float* __restrict__ b0,
                                                    const u16* __restrict__ W1,
                                                    u16* __restrict__ out0,
                                                    u16* __restrict__ out1,
                                                    const float* __restrict__ att_src,
                                                    const float* __restrict__ att_dst,
                                                    float* __restrict__ a_src,
                                                    float* __restrict__ a_dst, int nrows) {
    __shared__ __align__(16) u16 tA[128 * 128];
    __shared__ __align__(16) u16 tB[128 * 128];
    int t = threadIdx.x;
    int r0 = blockIdx.x * 128;
    #pragma unroll
    for (int it = 0; it < 8; ++it) {
        int idx = it * 256 + t;
        int r = idx >> 4, u = idx & 15;
        uint4 v = make_uint4(0u, 0u, 0u, 0u);
        if (r0 + r < nrows) v = *(const uint4*)(X + (size_t)(r0 + r) * 128 + u * 8);
        *(uint4*)&tA[tswz(r, u)] = v;
        uint4 wv = *(const uint4*)(W0 + (size_t)r * 128 + u * 8);
        *(uint4*)&tB[tswz(r, u)] = wv;
    }
    __syncthreads();
    int l = t & 63, w = t >> 6;
    int lr = l & 15, lk = l >> 4;
    f4 acc[2][8];
    #pragma unroll
    for (int m = 0; m < 2; ++m)
        #pragma unroll
        for (int n = 0; n < 8; ++n) acc[m][n] = (f4){0.f, 0.f, 0.f, 0.f};
    #pragma unroll
    for (int s = 0; s < 4; ++s) {
        int u = s * 4 + lk;
        h8 a0 = *(h8*)&tA[tswz(w * 32 + lr, u)];
        h8 a1 = *(h8*)&tA[tswz(w * 32 + 16 + lr, u)];
        #pragma unroll
        for (int n = 0; n < 8; ++n) {
            h8 b = *(h8*)&tB[tswz(n * 16 + lr, u)];
            acc[0][n] = __builtin_amdgcn_mfma_f32_16x16x32_f16(a0, b, acc[0][n], 0, 0, 0);
            acc[1][n] = __builtin_amdgcn_mfma_f32_16x16x32_f16(a1, b, acc[1][n], 0, 0, 0);
        }
    }
    #pragma unroll
    for (int n = 0; n < 8; ++n) {
        int col = n * 16 + lr;
        float bv = b0[col];
        #pragma unroll
        for (int m = 0; m < 2; ++m)
            #pragma unroll
            for (int g = 0; g < 4; ++g) {
                int row = r0 + w * 32 + m * 16 + lk * 4 + g;
                if (row < nrows) out0[(size_t)row * 128 + col] = f2h(acc[m][n][g] + bv);
            }
    }
    __syncthreads();   // all reads of tB done
    #pragma unroll
    for (int it = 0; it < 8; ++it) {
        int idx = it * 256 + t;
        int r = idx >> 4, u = idx & 15;
        uint4 wv = *(const uint4*)(W1 + (size_t)r * 128 + u * 8);
        *(uint4*)&tB[tswz(r, u)] = wv;
    }
    __syncthreads();
    #pragma unroll
    for (int m = 0; m < 2; ++m)
        #pragma unroll
        for (int n = 0; n < 8; ++n) acc[m][n] = (f4){0.f, 0.f, 0.f, 0.f};
    #pragma unroll
    for (int s = 0; s < 4; ++s) {
        int u = s * 4 + lk;
        h8 a0 = *(h8*)&tA[tswz(w * 32 + lr, u)];
        h8 a1 = *(h8*)&tA[tswz(w * 32 + 16 + lr, u)];
        #pragma unroll
        for (int n = 0; n < 8; ++n) {
            h8 b = *(h8*)&tB[tswz(n * 16 + lr, u)];
            acc[0][n] = __builtin_amdgcn_mfma_f32_16x16x32_f16(a0, b, acc[0][n], 0, 0, 0);
            acc[1][n] = __builtin_amdgcn_mfma_f32_16x16x32_f16(a1, b, acc[1][n], 0, 0, 0);
        }
    }
    #pragma unroll
    for (int n = 0; n < 8; ++n) {
        int col = n * 16 + lr;
        #pragma unroll
        for (int m = 0; m < 2; ++m)
            #pragma unroll
            for (int g = 0; g < 4; ++g) {
                int row = r0 + w * 32 + m * 16 + lk * 4 + g;
                if (row < nrows) out1[(size_t)row * 128 + col] = f2h(acc[m][n][g]);
            }
    }
    att_epilogue(acc, att_src, att_dst, a_src, a_dst, r0, w, lr, lk, nrows);
}

// ---------------------------------------------------------------------------
// fused JK MFMA GEMM: out_f32 = [h0 h1 h2]_f16 @ jk_w^T + jk_b (K=384)
// ---------------------------------------------------------------------------
__global__ __launch_bounds__(256, 2) void k_mfma_jk(const u16* __restrict__ h0,
                                                    const u16* __restrict__ h1,
                                                    const u16* __restrict__ h2,
                                                    const u16* __restrict__ W,
                                                    const float* __restrict__ bias,
                                                    float* __restrict__ out, int nrows) {
    __shared__ __align__(16) u16 tA[128 * 128];
    __shared__ __align__(16) u16 tB[128 * 128];
    int t = threadIdx.x;
    int r0 = blockIdx.x * 128;
    int l = t & 63, w = t >> 6;
    int lr = l & 15, lk = l >> 4;
    f4 acc[2][8];
    #pragma unroll
    for (int m = 0; m < 2; ++m)
        #pragma unroll
        for (int n = 0; n < 8; ++n) acc[m][n] = (f4){0.f, 0.f, 0.f, 0.f};
    for (int seg = 0; seg < 3; ++seg) {
        if (seg) __syncthreads();
        const u16* X = seg == 0 ? h0 : (seg == 1 ? h1 : h2);
        #pragma unroll
        for (int it = 0; it < 8; ++it) {
            int idx = it * 256 + t;
            int r = idx >> 4, u = idx & 15;
            uint4 v = make_uint4(0u, 0u, 0u, 0u);
            if (r0 + r < nrows) v = *(const uint4*)(X + (size_t)(r0 + r) * 128 + u * 8);
            *(uint4*)&tA[tswz(r, u)] = v;
            uint4 wv = *(const uint4*)(W + (size_t)r * 384 + seg * 128 + u * 8);
            *(uint4*)&tB[tswz(r, u)] = wv;
        }
        __syncthreads();
        #pragma unroll
        for (int s = 0; s < 4; ++s) {
            int u = s * 4 + lk;
            h8 a0 = *(h8*)&tA[tswz(w * 32 + lr, u)];
            h8 a1 = *(h8*)&tA[tswz(w * 32 + 16 + lr, u)];
            #pragma unroll
            for (int n = 0; n < 8; ++n) {
                h8 b = *(h8*)&tB[tswz(n * 16 + lr, u)];
                acc[0][n] = __builtin_amdgcn_mfma_f32_16x16x32_f16(a0, b, acc[0][n], 0, 0, 0);
                acc[1][n] = __builtin_amdgcn_mfma_f32_16x16x32_f16(a1, b, acc[1][n], 0, 0, 0);
            }
        }
    }
    #pragma unroll
    for (int n = 0; n < 8; ++n) {
        int col = n * 16 + lr;
        float bv = bias[col];
        #pragma unroll
        for (int m = 0; m < 2; ++m) {
            #pragma unroll
            for (int g = 0; g < 4; ++g) {
                int row = r0 + w * 32 + m * 16 + lk * 4 + g;
                if (row < nrows) out[(size_t)row * 128 + col] = acc[m][n][g] + bv;
            }
        }
    }
}

// ---------------------------------------------------------------------------
// aggregation over PADDED CSR, inline minimal-exp weights, waste-free
// bounds-checked prefetch pipeline (no gather block ever issued beyond en).
// ---------------------------------------------------------------------------
#define LOADBLK(S_, W_, X_, base_) { \
    int4 sv0 = *(const int4*)(srt_src + (base_)); \
    int4 sv1 = *(const int4*)(srt_src + (base_) + 4); \
    S_[0] = sv0.x; S_[1] = sv0.y; S_[2] = sv0.z; S_[3] = sv0.w; \
    S_[4] = sv1.x; S_[5] = sv1.y; S_[6] = sv1.z; S_[7] = sv1.w; \
    float aev = h2f(ae[(size_t)(base_) * 8 + lane]); \
    int sl = srt_src[(base_) + (lane >> 3)]; \
    float asv = a_src[(size_t)sl * 8 + hw]; \
    float alv = asv + adw + aev; \
    alv = alv > 0.f ? alv : 0.2f * alv; \
    float wvv = __expf(alv); \
    _Pragma("unroll") \
    for (int k = 0; k < 8; ++k) { \
        float ww = __shfl(wvv, (k << 3) | h, 64); \
        W_[k] = ((base_) + k < rend) ? ww : 0.f; } \
    _Pragma("unroll") \
    for (int k = 0; k < 8; ++k) \
        X_[k] = *(const unsigned*)(xs + (size_t)S_[k] * 128 + lane * 2); }

#define CPBLK(W_, X_) { \
    _Pragma("unroll") \
    for (int k = 0; k < 8; ++k) { \
        float wc = W_[k]; unsigned xv = X_[k]; \
        acc0 += wc * lo2f(xv); \
        acc1 += wc * hi2f(xv); \
        denom += wc; } }

__global__ __launch_bounds__(256) void k_agg(const int* __restrict__ rp,
                      const int* __restrict__ deg,
                      const int* __restrict__ srt_src,
                      const u16* __restrict__ ae,
                      const float* __restrict__ a_src, const float* __restrict__ a_dst,
                      const float* __restrict__ se,
                      const u16* __restrict__ xs, const u16* __restrict__ res,
                      const float* __restrict__ bias, const float* __restrict__ gamma,
                      const float* __restrict__ beta, u16* __restrict__ outh) {
    int wv_ = threadIdx.x >> 6, lane = threadIdx.x & 63;
    int i = blockIdx.x * 4 + wv_;
    if (i >= NN) return;
    int h = lane >> 3;                       // own head (features 2lane, 2lane+1)
    int hw = lane & 7;                       // weight-compute head
    int b0 = __builtin_amdgcn_readfirstlane(rp[i]);
    int en = __builtin_amdgcn_readfirstlane(rp[i + 1]);
    int rend = b0 + __builtin_amdgcn_readfirstlane(deg[i]);
    float adw = a_dst[i * 8 + hw];
    float acc0 = 0.f, acc1 = 0.f, denom = 0.f;
    if (b0 < en) {
        int SA[8], SB[8]; float WA[8], WB[8]; unsigned XA[8], XB[8];
        int base = b0;
        bool done = false;
        LOADBLK(SA, WA, XA, base)
        while (base + 8 < en) {
            LOADBLK(SB, WB, XB, base + 8)
            CPBLK(WA, XA)
            base += 8;
            if (base + 8 >= en) { CPBLK(WB, XB) done = true; break; }
            LOADBLK(SA, WA, XA, base + 8)
            CPBLK(WB, XB)
            base += 8;
        }
        if (!done) CPBLK(WA, XA)
    }
    {   // self loop (mean edge-attr folded to se[h])
        float al = a_src[i * 8 + h] + a_dst[i * 8 + h] + se[h];
        al = al > 0.f ? al : 0.2f * al;
        float wc = __expf(al);
        unsigned xv = *(const unsigned*)(xs + (size_t)i * 128 + lane * 2);
        denom += wc;
        acc0 += wc * lo2f(xv);
        acc1 += wc * hi2f(xv);
    }
    float inv = 1.f / (denom + 1e-16f);
    float2 bi = *(const float2*)(bias + lane * 2);
    float v0 = acc0 * inv + bi.x;
    float v1 = acc1 * inv + bi.y;
    v0 = v0 > 0.f ? v0 : (__expf(v0) - 1.f);
    v1 = v1 > 0.f ? v1 : (__expf(v1) - 1.f);
    unsigned rv = *(const unsigned*)(res + (size_t)i * 128 + lane * 2);
    v0 += lo2f(rv);
    v1 += hi2f(rv);
    float s = v0 + v1, q = v0 * v0 + v1 * v1;
    #pragma unroll
    for (int off = 1; off < 64; off <<= 1) { s += __shfl_xor(s, off, 64); q += __shfl_xor(q, off, 64); }
    float mu = s * (1.f / 128.f);
    float var = q * (1.f / 128.f) - mu * mu;
    float r = rsqrtf(var + 1e-5f);
    float2 ga = *(const float2*)(gamma + lane * 2);
    float2 be = *(const float2*)(beta + lane * 2);
    float o0 = (v0 - mu) * r * ga.x + be.x;
    float o1 = (v1 - mu) * r * ga.y + be.y;
    unsigned ov = (unsigned)f2h(o0) | ((unsigned)f2h(o1) << 16);
    *(unsigned*)(outh + (size_t)i * 128 + lane * 2) = ov;
}

// ---------------------------------------------------------------------------
extern "C" void kernel_launch(void* const* d_in, const int* in_sizes, int n_in,
                              void* d_out, int out_size, void* d_ws, size_t ws_size,
                              hipStream_t stream) {
    const float* x        = (const float*)d_in[0];
    const int*   ei       = (const int*)d_in[1];
    const float* enc_w1   = (const float*)d_in[2];
    const float* enc_b1   = (const float*)d_in[3];
    const float* enc_w2   = (const float*)d_in[4];
    const float* enc_b2   = (const float*)d_in[5];
    const float* in_w     = (const float*)d_in[6];
    const float* in_b     = (const float*)d_in[7];
    const float* lin_w1   = (const float*)d_in[8];
    const float* att_src1 = (const float*)d_in[9];
    const float* att_dst1 = (const float*)d_in[10];
    const float* att_edge1= (const float*)d_in[11];
    const float* lin_ew1  = (const float*)d_in[12];
    const float* bias1    = (const float*)d_in[13];
    const float* lin_w2   = (const float*)d_in[14];
    const float* att_src2 = (const float*)d_in[15];
    const float* att_dst2 = (const float*)d_in[16];
    const float* att_edge2= (const float*)d_in[17];
    const float* lin_ew2  = (const float*)d_in[18];
    const float* bias2    = (const float*)d_in[19];
    const float* g1       = (const float*)d_in[20];
    const float* bn1      = (const float*)d_in[21];
    const float* g2       = (const float*)d_in[22];
    const float* bn2      = (const float*)d_in[23];
    const float* jk_w     = (const float*)d_in[24];
    const float* jk_b     = (const float*)d_in[25];
    float* out = (float*)d_out;

    char* wsp = (char*)d_ws;
    size_t off = 0;
    auto alloc = [&](size_t bytes) -> char* {
        char* p = wsp + off;
        off += (bytes + 255) & ~(size_t)255;
        return p;
    };
    u16* x_bf   = (u16*)alloc(sizeof(u16) * (size_t)NN * 128);
    u16* h0b    = (u16*)alloc(sizeof(u16) * (size_t)NN * 128);
    u16* h1b    = (u16*)alloc(sizeof(u16) * (size_t)NN * 128);
    u16* h2b    = (u16*)alloc(sizeof(u16) * (size_t)NN * 128);
    u16* xsb    = (u16*)alloc(sizeof(u16) * (size_t)NN * 128);
    u16* inw_b  = (u16*)alloc(sizeof(u16) * 16384);
    u16* w1_b   = (u16*)alloc(sizeof(u16) * 16384);
    u16* w2_b   = (u16*)alloc(sizeof(u16) * 16384);
    u16* jkw_b  = (u16*)alloc(sizeof(u16) * 49152);
    u16* ae1    = (u16*)alloc(sizeof(u16) * (size_t)EPAD * 8);
    u16* ae2    = (u16*)alloc(sizeof(u16) * (size_t)EPAD * 8);
    float* norms = (float*)alloc(sizeof(float) * NN);
    float* a_src1= (float*)alloc(sizeof(float) * NN * 8);
    float* a_dst1= (float*)alloc(sizeof(float) * NN * 8);
    float* a_src2= (float*)alloc(sizeof(float) * NN * 8);
    float* a_dst2= (float*)alloc(sizeof(float) * NN * 8);
    float* P1    = (float*)alloc(sizeof(float) * 128);
    float* q1    = (float*)alloc(sizeof(float) * 8);
    float* P2    = (float*)alloc(sizeof(float) * 128);
    float* q2    = (float*)alloc(sizeof(float) * 8);
    float* se1   = (float*)alloc(sizeof(float) * 8);
    float* se2   = (float*)alloc(sizeof(float) * 8);
    // zero-init region: deg + sums + done contiguous, single memset
    int* deg     = (int*)alloc(sizeof(int) * NN);
    float* sums  = (float*)alloc(sizeof(float) * 16);
    unsigned* done = (unsigned*)alloc(sizeof(unsigned));
    int* rp      = (int*)alloc(sizeof(int) * (NN + 1));
    int* cursor  = (int*)alloc(sizeof(int) * NN);
    int* bsum    = (int*)alloc(sizeof(int) * NBLK);
    int* srt_src = (int*)alloc(sizeof(int) * EPAD);
    int* srt_dst = (int*)alloc(sizeof(int) * EPAD);
    (void)ws_size; (void)in_sizes; (void)n_in; (void)out_size;
    const int* epad_ptr = rp + NN;

    hipMemsetAsync(deg, 0, (size_t)((char*)rp - (char*)deg), stream);

    // mega prep: node norms/cvt + weight cvt + precompute + degree hist
    k_prep<<<NBP + 48 + 1 + (EE + 255) / 256, 256, 0, stream>>>(
        x, norms, x_bf,
        in_w, inw_b, lin_w1, w1_b, lin_w2, w2_b, jk_w, jkw_b,
        lin_ew1, att_edge1, lin_ew2, att_edge2, enc_w2, enc_b2, P1, q1, P2, q2,
        ei, deg);
    k_scan1<<<NBLK, 256, 0, stream>>>(deg, bsum);
    k_scan2<<<1, 256, 0, stream>>>(bsum, rp);
    k_scan3<<<NBLK, 256, 0, stream>>>(deg, bsum, rp, cursor);
    k_scatter<<<SCB + (NN + 255) / 256, 256, 0, stream>>>(ei, cursor, deg, rp,
                                                          srt_src, srt_dst, ae1, ae2);
    k_encoder<<<(EPAD + 63) / 64, 256, 0, stream>>>(x_bf, srt_src, srt_dst, norms, enc_w1, enc_b1,
                                                    P1, q1, P2, q2, ae1, ae2, epad_ptr);
    k_redsum<<<512, 256, 0, stream>>>(ae1, ae2, sums, done, se1, se2, epad_ptr);

    int gm = (NN + 127) / 128;
    k_mfma_x2<<<gm, 256, 0, stream>>>(x_bf, inw_b, in_b, w1_b, h0b, xsb,
                                      att_src1, att_dst1, a_src1, a_dst1, NN);
    k_agg<<<(NN + 3) / 4, 256, 0, stream>>>(rp, deg, srt_src, ae1, a_src1, a_dst1, se1,
                                            xsb, h0b, bias1, g1, bn1, h1b);
    k_mfma<false, true><<<gm, 256, 0, stream>>>(h1b, w2_b, nullptr, xsb,
                                                att_src2, att_dst2, a_src2, a_dst2, NN);
    k_agg<<<(NN + 3) / 4, 256, 0, stream>>>(rp, deg, srt_src, ae2, a_src2, a_dst2, se2,
                                            xsb, h1b, bias2, g2, bn2, h2b);
    k_mfma_jk<<<gm, 256, 0, stream>>>(h0b, h1b, h2b, jkw_b, jk_b, out, NN);
}

// Round 16
// 309.628 us; speedup vs baseline: 1.0748x; 1.0748x over previous
//
#include <hip/hip_runtime.h>

#define NN 50000
#define EE 600000
#define FF 128
#define HH 8
#define CC 16
#define DD 128
#define EPAD 950272   // >= EE + 7*NN + 24 sentinels
#define NBLK 196      // ceil(NN/256)

typedef unsigned short u16;
typedef _Float16 h2t __attribute__((ext_vector_type(2)));
typedef _Float16 h8 __attribute__((ext_vector_type(8)));
typedef float f4 __attribute__((ext_vector_type(4)));

#if defined(__has_builtin)
#if __has_builtin(__builtin_amdgcn_fdot2)
#define HAS_FDOT2 1
#endif
#endif

static __device__ __forceinline__ float h2f(u16 u) {
    _Float16 h; __builtin_memcpy(&h, &u, 2); return (float)h;
}
static __device__ __forceinline__ u16 f2h(float f) {
    _Float16 h = (_Float16)f; u16 u; __builtin_memcpy(&u, &h, 2); return u;
}
static __device__ __forceinline__ float lo2f(unsigned x) { return h2f((u16)(x & 0xffff)); }
static __device__ __forceinline__ float hi2f(unsigned x) { return h2f((u16)(x >> 16)); }

static __device__ __forceinline__ float dot8(uint4 a, uint4 b, float c) {
#ifdef HAS_FDOT2
    h2t ax[4], bx[4];
    __builtin_memcpy(&ax, &a, 16); __builtin_memcpy(&bx, &b, 16);
    c = __builtin_amdgcn_fdot2(ax[0], bx[0], c, false);
    c = __builtin_amdgcn_fdot2(ax[1], bx[1], c, false);
    c = __builtin_amdgcn_fdot2(ax[2], bx[2], c, false);
    c = __builtin_amdgcn_fdot2(ax[3], bx[3], c, false);
#else
    c += lo2f(a.x) * lo2f(b.x) + hi2f(a.x) * hi2f(b.x)
       + lo2f(a.y) * lo2f(b.y) + hi2f(a.y) * hi2f(b.y)
       + lo2f(a.z) * lo2f(b.z) + hi2f(a.z) * hi2f(b.z)
       + lo2f(a.w) * lo2f(b.w) + hi2f(a.w) * hi2f(b.w);
#endif
    return c;
}
static __device__ __forceinline__ float dot8h(uint4 a, const h2t* pk, float c) {
#ifdef HAS_FDOT2
    h2t ax[4];
    __builtin_memcpy(&ax, &a, 16);
    c = __builtin_amdgcn_fdot2(ax[0], pk[0], c, false);
    c = __builtin_amdgcn_fdot2(ax[1], pk[1], c, false);
    c = __builtin_amdgcn_fdot2(ax[2], pk[2], c, false);
    c = __builtin_amdgcn_fdot2(ax[3], pk[3], c, false);
#else
    c += lo2f(a.x) * (float)pk[0][0] + hi2f(a.x) * (float)pk[0][1]
       + lo2f(a.y) * (float)pk[1][0] + hi2f(a.y) * (float)pk[1][1]
       + lo2f(a.z) * (float)pk[2][0] + hi2f(a.z) * (float)pk[2][1]
       + lo2f(a.w) * (float)pk[3][0] + hi2f(a.w) * (float)pk[3][1];
#endif
    return c;
}

// LDS tile swizzle: tile is [128 rows][128 f16]; 16B-unit index with XOR
static __device__ __forceinline__ int tswz(int row, int u) {
    return (row * 16 + (u ^ (row & 7))) * 8;   // u16 element index
}

// ---------------------------------------------------------------------------
// MEGA prep kernel: node norms + x->f16 | weight cvt | precompute | histogram
// ---------------------------------------------------------------------------
#define NBP 12500
__global__ void k_prep(const float* __restrict__ x, float* __restrict__ norms,
                       u16* __restrict__ xb,
                       const float* __restrict__ s0, u16* __restrict__ d0,
                       const float* __restrict__ s1, u16* __restrict__ d1,
                       const float* __restrict__ s2, u16* __restrict__ d2,
                       const float* __restrict__ s3, u16* __restrict__ d3,
                       const float* __restrict__ lew1, const float* __restrict__ aew1,
                       const float* __restrict__ lew2, const float* __restrict__ aew2,
                       const float* __restrict__ enc_w2, const float* __restrict__ enc_b2,
                       float* __restrict__ P1, float* __restrict__ q1,
                       float* __restrict__ P2, float* __restrict__ q2,
                       const int* __restrict__ ei, int* __restrict__ deg) {
    __shared__ float sM1[64], sM2[64];
    int bb = blockIdx.x;
    int t = threadIdx.x;
    if (bb < NBP) {
        int wid = t >> 6, lane = t & 63;
        int row = bb * 4 + wid;
        float2 v = ((const float2*)(x + (size_t)row * FF))[lane];
        float s = v.x * v.x + v.y * v.y;
        #pragma unroll
        for (int off = 1; off < 64; off <<= 1) s += __shfl_xor(s, off, 64);
        if (lane == 0) norms[row] = s;
        unsigned pk = (unsigned)f2h(v.x) | ((unsigned)f2h(v.y) << 16);
        *(unsigned*)(xb + (size_t)row * FF + lane * 2) = pk;
    } else if (bb < NBP + 48) {
        int b = bb - NBP;
        const float* s; u16* d; int base;
        if (b < 8)       { s = s0; d = d0; base = b * 2048; }
        else if (b < 16) { s = s1; d = d1; base = (b - 8) * 2048; }
        else if (b < 24) { s = s2; d = d2; base = (b - 16) * 2048; }
        else             { s = s3; d = d3; base = (b - 24) * 2048; }
        int i = base + t * 8;
        float4 v0 = *(const float4*)(s + i);
        float4 v1 = *(const float4*)(s + i + 4);
        u16 o[8] = {f2h(v0.x), f2h(v0.y), f2h(v0.z), f2h(v0.w),
                    f2h(v1.x), f2h(v1.y), f2h(v1.z), f2h(v1.w)};
        *(uint4*)(d + i) = *(uint4*)o;
    } else if (bb == NBP + 48) {
        if (t < 128) {
            int kk = (t & 63) >> 3, h = t & 7;
            const float* lew = (t < 64) ? lew1 : lew2;
            const float* ae  = (t < 64) ? aew1 : aew2;
            float s = 0.f;
            for (int c = 0; c < 16; ++c) s += lew[(h * 16 + c) * 8 + kk] * ae[h * 16 + c];
            if (t < 64) sM1[kk * 8 + h] = s; else sM2[kk * 8 + h] = s;
        }
        __syncthreads();
        if (t < 128) {
            int c = t >> 3, h = t & 7;
            float p1 = 0.f, p2 = 0.f;
            for (int k = 0; k < 8; ++k) {
                float w = enc_w2[k * 16 + c];
                p1 += w * sM1[k * 8 + h];
                p2 += w * sM2[k * 8 + h];
            }
            P1[c * 8 + h] = p1;
            P2[c * 8 + h] = p2;
            if (t < 8) {
                float x1 = 0.f, x2 = 0.f;
                for (int k = 0; k < 8; ++k) { float b = enc_b2[k]; x1 += b * sM1[k * 8 + t]; x2 += b * sM2[k * 8 + t]; }
                q1[t] = x1; q2[t] = x2;
            }
        }
    } else {
        int e = (bb - NBP - 49) * 256 + t;
        if (e < EE) atomicAdd(&deg[ei[EE + e]], 1);
    }
}

// ---------------------------------------------------------------------------
// 3-phase multi-block exclusive scan of padded degrees
// ---------------------------------------------------------------------------
__global__ void k_scan1(const int* __restrict__ deg, int* __restrict__ bsum) {
    int t = threadIdx.x, wid = t >> 6, lane = t & 63;
    int i = blockIdx.x * 256 + t;
    int v = (i < NN) ? ((deg[i] + 7) & ~7) : 0;
    #pragma unroll
    for (int off = 1; off < 64; off <<= 1) v += __shfl_xor(v, off, 64);
    __shared__ int ws[4];
    if (lane == 0) ws[wid] = v;
    __syncthreads();
    if (t == 0) bsum[blockIdx.x] = ws[0] + ws[1] + ws[2] + ws[3];
}

__global__ void k_scan2(int* __restrict__ bsum, int* __restrict__ rp) {
    int t = threadIdx.x, wid = t >> 6, lane = t & 63;
    int v = (t < NBLK) ? bsum[t] : 0;
    int sc = v;
    #pragma unroll
    for (int off = 1; off < 64; off <<= 1) { int n = __shfl_up(sc, off, 64); if (lane >= off) sc += n; }
    __shared__ int ws[4], wso[4];
    if (lane == 63) ws[wid] = sc;
    __syncthreads();
    if (t == 0) {
        int c = 0;
        for (int k = 0; k < 4; ++k) { wso[k] = c; c += ws[k]; }
        rp[NN] = c;
    }
    __syncthreads();
    if (t < NBLK) bsum[t] = sc - v + wso[wid];
}

__global__ void k_scan3(const int* __restrict__ deg, const int* __restrict__ bsum,
                        int* __restrict__ rp, int* __restrict__ cursor) {
    int t = threadIdx.x, wid = t >> 6, lane = t & 63;
    int i = blockIdx.x * 256 + t;
    int v = (i < NN) ? ((deg[i] + 7) & ~7) : 0;
    int sc = v;
    #pragma unroll
    for (int off = 1; off < 64; off <<= 1) { int n = __shfl_up(sc, off, 64); if (lane >= off) sc += n; }
    __shared__ int ws[4], wso[4];
    if (lane == 63) ws[wid] = sc;
    __syncthreads();
    if (t == 0) {
        int c = 0;
        for (int k = 0; k < 4; ++k) { wso[k] = c; c += ws[k]; }
    }
    __syncthreads();
    int ex = bsum[blockIdx.x] + wso[wid] + sc - v;
    if (i < NN) { rp[i] = ex; cursor[i] = ex; }
}

// ---------------------------------------------------------------------------
// scatter (real edges) + fill (padding + sentinels + sentinel-ae zero)
// ---------------------------------------------------------------------------
#define SCB 2344   // ceil(EE/256)
__global__ void k_scatter(const int* __restrict__ ei, int* __restrict__ cursor,
                          const int* __restrict__ deg, const int* __restrict__ rp,
                          int* __restrict__ srt_src, int* __restrict__ srt_dst,
                          u16* __restrict__ ae1, u16* __restrict__ ae2) {
    int bb = blockIdx.x;
    if (bb < SCB) {
        int e = bb * 256 + threadIdx.x;
        if (e < EE) {
            int d = ei[EE + e];
            int pos = atomicAdd(&cursor[d], 1);
            srt_src[pos] = ei[e];
            srt_dst[pos] = d;
        }
    } else {
        int i = (bb - SCB) * 256 + threadIdx.x;
        if (i < NN) {
            int start = rp[i] + deg[i], end = rp[i + 1];
            for (int p = start; p < end; ++p) { srt_src[p] = i; srt_dst[p] = -1; }
        }
        if (i == 0) {
            int ep = rp[NN];
            for (int k = 0; k < 24; ++k) { srt_src[ep + k] = 0; srt_dst[ep + k] = -1; }
            for (int k = 0; k < 192; ++k) { ae1[(size_t)ep * 8 + k] = 0; ae2[(size_t)ep * 8 + k] = 0; }
        }
    }
}

// ---------------------------------------------------------------------------
// K2: edge encoder. 16 lanes/edge, 4 edges/thread. f16 hid exchange in
// unpadded [16][16] LDS, P as f16 pairs via fdot2. Pad edges skip gathers.
// ---------------------------------------------------------------------------
__global__ void k_encoder(const u16* __restrict__ xb,
                          const int* __restrict__ srt_src, const int* __restrict__ srt_dst,
                          const float* __restrict__ norms,
                          const float* __restrict__ enc_w1, const float* __restrict__ enc_b1,
                          const float* __restrict__ P1, const float* __restrict__ q1,
                          const float* __restrict__ P2, const float* __restrict__ q2,
                          u16* __restrict__ ae1out, u16* __restrict__ ae2out,
                          const int* __restrict__ epad) {
    __shared__ __align__(16) u16 hidbuf[16][16];
    int t = threadIdx.x, eq = t >> 4, l = t & 15;
    int conv = l >> 3, h = l & 7;
    int EP = *epad;
    float w0 = enc_w1[l * 4 + 0], w1 = enc_w1[l * 4 + 1];
    float w2 = enc_w1[l * 4 + 2], w3 = enc_w1[l * 4 + 3];
    float cA = w0 - 2.f * w1, cB = w1 + w2, cC = w1 + w3, cb = enc_b1[l];
    const float* Ps = conv ? P2 : P1;
    h2t pk[8];
    #pragma unroll
    for (int c = 0; c < 8; ++c)
        pk[c] = (h2t){(_Float16)Ps[(2 * c) * 8 + h], (_Float16)Ps[(2 * c + 1) * 8 + h]};
    float qreg = conv ? q2[h] : q1[h];
    u16* outp = conv ? ae2out : ae1out;
    int e0 = blockIdx.x * 64 + eq;
    int ss[4], dc[4]; bool ok[4], inr[4];
    #pragma unroll
    for (int j = 0; j < 4; ++j) {
        int e = e0 + j * 16;
        inr[j] = e < EP;
        int eidx = inr[j] ? e : 0;
        int d_ = srt_dst[eidx];
        ss[j] = srt_src[eidx];
        ok[j] = inr[j] && (d_ >= 0);
        dc[j] = d_ >= 0 ? d_ : ss[j];
    }
    uint4 av[4], bv[4];
    float ni[4], nj[4];
    #pragma unroll
    for (int j = 0; j < 4; ++j) {
        if (ok[j]) {
            av[j] = *(const uint4*)(xb + (size_t)ss[j] * FF + l * 8);
            bv[j] = *(const uint4*)(xb + (size_t)dc[j] * FF + l * 8);
            ni[j] = norms[ss[j]]; nj[j] = norms[dc[j]];
        }
    }
    #pragma unroll
    for (int j = 0; j < 4; ++j) {
        if (!inr[j]) continue;
        int e = e0 + j * 16;
        if (!ok[j]) { outp[(size_t)e * 8 + h] = 0; continue; }
        float dot = dot8(av[j], bv[j], 0.f);
        #pragma unroll
        for (int off = 1; off < 16; off <<= 1) dot += __shfl_xor(dot, off, 64);
        float v = cA * dot + cB * ni[j] + cC * nj[j] + cb;
        hidbuf[eq][l] = f2h(v > 0.f ? v : 0.f);
        uint4 h0v = *(const uint4*)&hidbuf[eq][0];
        uint4 h1v = *(const uint4*)&hidbuf[eq][8];
        float a = dot8h(h0v, pk, qreg);
        a = dot8h(h1v, pk + 4, a);
        outp[(size_t)e * 8 + h] = f2h(a);
    }
}

// ---------------------------------------------------------------------------
// K2b: uint4 grid-stride reduction of f16 ae1/ae2 -> sums[16]; one uint4 =
// one edge's 8 heads. Last block computes se1/se2.
// ---------------------------------------------------------------------------
__global__ void k_redsum(const u16* __restrict__ a1, const u16* __restrict__ a2,
                         float* __restrict__ sums, unsigned* __restrict__ done,
                         float* __restrict__ se1, float* __restrict__ se2,
                         const int* __restrict__ epad) {
    int tid = threadIdx.x;  // 256
    int nck = *epad;        // uint4 chunks (one per edge position)
    int gid = blockIdx.x * 256 + tid;
    int stride = gridDim.x * 256;
    float c1[8] = {}, c2[8] = {};
    for (int i = gid; i < nck; i += stride) {
        uint4 v1 = ((const uint4*)a1)[i];
        uint4 v2 = ((const uint4*)a2)[i];
        c1[0] += lo2f(v1.x); c1[1] += hi2f(v1.x); c1[2] += lo2f(v1.y); c1[3] += hi2f(v1.y);
        c1[4] += lo2f(v1.z); c1[5] += hi2f(v1.z); c1[6] += lo2f(v1.w); c1[7] += hi2f(v1.w);
        c2[0] += lo2f(v2.x); c2[1] += hi2f(v2.x); c2[2] += lo2f(v2.y); c2[3] += hi2f(v2.y);
        c2[4] += lo2f(v2.z); c2[5] += hi2f(v2.z); c2[6] += lo2f(v2.w); c2[7] += hi2f(v2.w);
    }
    #pragma unroll
    for (int off = 1; off < 64; off <<= 1) {
        #pragma unroll
        for (int k = 0; k < 8; ++k) {
            c1[k] += __shfl_xor(c1[k], off, 64);
            c2[k] += __shfl_xor(c2[k], off, 64);
        }
    }
    __shared__ float b1[4][8], b2[4][8];
    int wid = tid >> 6, lane = tid & 63;
    if (lane == 0) {
        #pragma unroll
        for (int k = 0; k < 8; ++k) { b1[wid][k] = c1[k]; b2[wid][k] = c2[k]; }
    }
    __syncthreads();
    if (tid < 8) {
        float t1 = b1[0][tid] + b1[1][tid] + b1[2][tid] + b1[3][tid];
        float t2 = b2[0][tid] + b2[1][tid] + b2[2][tid] + b2[3][tid];
        atomicAdd(&sums[tid], t1);
        atomicAdd(&sums[8 + tid], t2);
    }
    __syncthreads();
    if (tid == 0) {
        __threadfence();
        unsigned old = atomicAdd(done, 1u);
        if (old == (unsigned)gridDim.x - 1u) {
            __threadfence();
            for (int hh = 0; hh < 8; ++hh) {
                float v1 = atomicAdd(&sums[hh], 0.f);
                float v2 = atomicAdd(&sums[8 + hh], 0.f);
                se1[hh] = v1 * (1.f / (float)EE);
                se2[hh] = v2 * (1.f / (float)EE);
            }
        }
    }
}

// ---------------------------------------------------------------------------
// att epilogue: per-row per-head dots with att vectors, 16-lane xor reduce
// ---------------------------------------------------------------------------
static __device__ __forceinline__ void att_epilogue(const f4 (&acc)[2][8],
        const float* __restrict__ att_src, const float* __restrict__ att_dst,
        float* __restrict__ a_src, float* __restrict__ a_dst,
        int r0, int w, int lr, int lk, int nrows) {
    float attS[8], attD[8];
    #pragma unroll
    for (int n = 0; n < 8; ++n) { attS[n] = att_src[n * 16 + lr]; attD[n] = att_dst[n * 16 + lr]; }
    int hh = lr & 7;
    #pragma unroll
    for (int m = 0; m < 2; ++m) {
        #pragma unroll
        for (int g = 0; g < 4; ++g) {
            float sv[8], dv[8];
            #pragma unroll
            for (int n = 0; n < 8; ++n) { float p = acc[m][n][g]; sv[n] = p * attS[n]; dv[n] = p * attD[n]; }
            #pragma unroll
            for (int off = 1; off < 16; off <<= 1) {
                #pragma unroll
                for (int n = 0; n < 8; ++n) {
                    sv[n] += __shfl_xor(sv[n], off, 64);
                    dv[n] += __shfl_xor(dv[n], off, 64);
                }
            }
            float so = lr < 8 ? sv[0] : dv[0];
            #pragma unroll
            for (int n = 1; n < 8; ++n) { float c = lr < 8 ? sv[n] : dv[n]; so = (hh == n) ? c : so; }
            int row = r0 + w * 32 + m * 16 + lk * 4 + g;
            if (row < nrows) {
                float* p = lr < 8 ? a_src : a_dst;
                p[(size_t)row * 8 + hh] = so;
            }
        }
    }
}

// ---------------------------------------------------------------------------
// f16 MFMA GEMM (+optional fused att scores)
// ---------------------------------------------------------------------------
template <bool BIAS, bool ATT>
__global__ __launch_bounds__(256, 2) void k_mfma(const u16* __restrict__ X,
                                                 const u16* __restrict__ W,
                                                 const float* __restrict__ bias,
                                                 u16* __restrict__ out,
                                                 const float* __restrict__ att_src,
                                                 const float* __restrict__ att_dst,
                                                 float* __restrict__ a_src,
                                                 float* __restrict__ a_dst, int nrows) {
    __shared__ __align__(16) u16 tA[128 * 128];
    __shared__ __align__(16) u16 tB[128 * 128];
    int t = threadIdx.x;
    int r0 = blockIdx.x * 128;
    #pragma unroll
    for (int it = 0; it < 8; ++it) {
        int idx = it * 256 + t;
        int r = idx >> 4, u = idx & 15;
        uint4 v = make_uint4(0u, 0u, 0u, 0u);
        if (r0 + r < nrows) v = *(const uint4*)(X + (size_t)(r0 + r) * 128 + u * 8);
        *(uint4*)&tA[tswz(r, u)] = v;
        uint4 wv = *(const uint4*)(W + (size_t)r * 128 + u * 8);
        *(uint4*)&tB[tswz(r, u)] = wv;
    }
    __syncthreads();
    int l = t & 63, w = t >> 6;
    int lr = l & 15, lk = l >> 4;
    f4 acc[2][8];
    #pragma unroll
    for (int m = 0; m < 2; ++m)
        #pragma unroll
        for (int n = 0; n < 8; ++n) acc[m][n] = (f4){0.f, 0.f, 0.f, 0.f};
    #pragma unroll
    for (int s = 0; s < 4; ++s) {
        int u = s * 4 + lk;
        h8 a0 = *(h8*)&tA[tswz(w * 32 + lr, u)];
        h8 a1 = *(h8*)&tA[tswz(w * 32 + 16 + lr, u)];
        #pragma unroll
        for (int n = 0; n < 8; ++n) {
            h8 b = *(h8*)&tB[tswz(n * 16 + lr, u)];
            acc[0][n] = __builtin_amdgcn_mfma_f32_16x16x32_f16(a0, b, acc[0][n], 0, 0, 0);
            acc[1][n] = __builtin_amdgcn_mfma_f32_16x16x32_f16(a1, b, acc[1][n], 0, 0, 0);
        }
    }
    #pragma unroll
    for (int n = 0; n < 8; ++n) {
        int col = n * 16 + lr;
        float bv = BIAS ? bias[col] : 0.f;
        #pragma unroll
        for (int m = 0; m < 2; ++m) {
            #pragma unroll
            for (int g = 0; g < 4; ++g) {
                int row = r0 + w * 32 + m * 16 + lk * 4 + g;
                if (row < nrows) out[(size_t)row * 128 + col] = f2h(acc[m][n][g] + bv);
            }
        }
    }
    if (ATT) att_epilogue(acc, att_src, att_dst, a_src, a_dst, r0, w, lr, lk, nrows);
}

// ---------------------------------------------------------------------------
// fused dual GEMM on shared A-tile: out0 = X@W0^T + b0;  out1 = X@W1^T (+att)
// ---------------------------------------------------------------------------
__global__ __launch_bounds__(256, 2) void k_mfma_x2(const u16* __restrict__ X,
                                                    const u16* __restrict__ W0,
                                                    const float* __restrict__ b0,
                                                    const u16* __restrict__ W1,
                                                    u16* __restrict__ out0,
                                                    u16* __restrict__ out1,
                                                    const float* __restrict__ att_src,
                                                    const float* __restrict__ att_dst,
                                                    float* __restrict__ a_src,
                                                    float* __restrict__ a_dst, int nrows) {
    __shared__ __align__(16) u16 tA[128 * 128];
    __shared__ __align__(16) u16 tB[128 * 128];
    int t = threadIdx.x;
    int r0 = blockIdx.x * 128;
    #pragma unroll
    for (int it = 0; it < 8; ++it) {
        int idx = it * 256 + t;
        int r = idx >> 4, u = idx & 15;
        uint4 v = make_uint4(0u, 0u, 0u, 0u);
        if (r0 + r < nrows) v = *(const uint4*)(X + (size_t)(r0 + r) * 128 + u * 8);
        *(uint4*)&tA[tswz(r, u)] = v;
        uint4 wv = *(const uint4*)(W0 + (size_t)r * 128 + u * 8);
        *(uint4*)&tB[tswz(r, u)] = wv;
    }
    __syncthreads();
    int l = t & 63, w = t >> 6;
    int lr = l & 15, lk = l >> 4;
    f4 acc[2][8];
    #pragma unroll
    for (int m = 0; m < 2; ++m)
        #pragma unroll
        for (int n = 0; n < 8; ++n) acc[m][n] = (f4){0.f, 0.f, 0.f, 0.f};
    #pragma unroll
    for (int s = 0; s < 4; ++s) {
        int u = s * 4 + lk;
        h8 a0 = *(h8*)&tA[tswz(w * 32 + lr, u)];
        h8 a1 = *(h8*)&tA[tswz(w * 32 + 16 + lr, u)];
        #pragma unroll
        for (int n = 0; n < 8; ++n) {
            h8 b = *(h8*)&tB[tswz(n * 16 + lr, u)];
            acc[0][n] = __builtin_amdgcn_mfma_f32_16x16x32_f16(a0, b, acc[0][n], 0, 0, 0);
            acc[1][n] = __builtin_amdgcn_mfma_f32_16x16x32_f16(a1, b, acc[1][n], 0, 0, 0);
        }
    }
    #pragma unroll
    for (int n = 0; n < 8; ++n) {
        int col = n * 16 + lr;
        float bv = b0[col];
        #pragma unroll
        for (int m = 0; m < 2; ++m)
            #pragma unroll
            for (int g = 0; g < 4; ++g) {
                int row = r0 + w * 32 + m * 16 + lk * 4 + g;
                if (row < nrows) out0[(size_t)row * 128 + col] = f2h(acc[m][n][g] + bv);
            }
    }
    __syncthreads();   // all reads of tB done
    #pragma unroll
    for (int it = 0; it < 8; ++it) {
        int idx = it * 256 + t;
        int r = idx >> 4, u = idx & 15;
        uint4 wv = *(const uint4*)(W1 + (size_t)r * 128 + u * 8);
        *(uint4*)&tB[tswz(r, u)] = wv;
    }
    __syncthreads();
    #pragma unroll
    for (int m = 0; m < 2; ++m)
        #pragma unroll
        for (int n = 0; n < 8; ++n) acc[m][n] = (f4){0.f, 0.f, 0.f, 0.f};
    #pragma unroll
    for (int s = 0; s < 4; ++s) {
        int u = s * 4 + lk;
        h8 a0 = *(h8*)&tA[tswz(w * 32 + lr, u)];
        h8 a1 = *(h8*)&tA[tswz(w * 32 + 16 + lr, u)];
        #pragma unroll
        for (int n = 0; n < 8; ++n) {
            h8 b = *(h8*)&tB[tswz(n * 16 + lr, u)];
            acc[0][n] = __builtin_amdgcn_mfma_f32_16x16x32_f16(a0, b, acc[0][n], 0, 0, 0);
            acc[1][n] = __builtin_amdgcn_mfma_f32_16x16x32_f16(a1, b, acc[1][n], 0, 0, 0);
        }
    }
    #pragma unroll
    for (int n = 0; n < 8; ++n) {
        int col = n * 16 + lr;
        #pragma unroll
        for (int m = 0; m < 2; ++m)
            #pragma unroll
            for (int g = 0; g < 4; ++g) {
                int row = r0 + w * 32 + m * 16 + lk * 4 + g;
                if (row < nrows) out1[(size_t)row * 128 + col] = f2h(acc[m][n][g]);
            }
    }
    att_epilogue(acc, att_src, att_dst, a_src, a_dst, r0, w, lr, lk, nrows);
}

// ---------------------------------------------------------------------------
// fused JK MFMA GEMM: out_f32 = [h0 h1 h2]_f16 @ jk_w^T + jk_b (K=384)
// ---------------------------------------------------------------------------
__global__ __launch_bounds__(256, 2) void k_mfma_jk(const u16* __restrict__ h0,
                                                    const u16* __restrict__ h1,
                                                    const u16* __restrict__ h2,
                                                    const u16* __restrict__ W,
                                                    const float* __restrict__ bias,
                                                    float* __restrict__ out, int nrows) {
    __shared__ __align__(16) u16 tA[128 * 128];
    __shared__ __align__(16) u16 tB[128 * 128];
    int t = threadIdx.x;
    int r0 = blockIdx.x * 128;
    int l = t & 63, w = t >> 6;
    int lr = l & 15, lk = l >> 4;
    f4 acc[2][8];
    #pragma unroll
    for (int m = 0; m < 2; ++m)
        #pragma unroll
        for (int n = 0; n < 8; ++n) acc[m][n] = (f4){0.f, 0.f, 0.f, 0.f};
    for (int seg = 0; seg < 3; ++seg) {
        if (seg) __syncthreads();
        const u16* X = seg == 0 ? h0 : (seg == 1 ? h1 : h2);
        #pragma unroll
        for (int it = 0; it < 8; ++it) {
            int idx = it * 256 + t;
            int r = idx >> 4, u = idx & 15;
            uint4 v = make_uint4(0u, 0u, 0u, 0u);
            if (r0 + r < nrows) v = *(const uint4*)(X + (size_t)(r0 + r) * 128 + u * 8);
            *(uint4*)&tA[tswz(r, u)] = v;
            uint4 wv = *(const uint4*)(W + (size_t)r * 384 + seg * 128 + u * 8);
            *(uint4*)&tB[tswz(r, u)] = wv;
        }
        __syncthreads();
        #pragma unroll
        for (int s = 0; s < 4; ++s) {
            int u = s * 4 + lk;
            h8 a0 = *(h8*)&tA[tswz(w * 32 + lr, u)];
            h8 a1 = *(h8*)&tA[tswz(w * 32 + 16 + lr, u)];
            #pragma unroll
            for (int n = 0; n < 8; ++n) {
                h8 b = *(h8*)&tB[tswz(n * 16 + lr, u)];
                acc[0][n] = __builtin_amdgcn_mfma_f32_16x16x32_f16(a0, b, acc[0][n], 0, 0, 0);
                acc[1][n] = __builtin_amdgcn_mfma_f32_16x16x32_f16(a1, b, acc[1][n], 0, 0, 0);
            }
        }
    }
    #pragma unroll
    for (int n = 0; n < 8; ++n) {
        int col = n * 16 + lr;
        float bv = bias[col];
        #pragma unroll
        for (int m = 0; m < 2; ++m) {
            #pragma unroll
            for (int g = 0; g < 4; ++g) {
                int row = r0 + w * 32 + m * 16 + lk * 4 + g;
                if (row < nrows) out[(size_t)row * 128 + col] = acc[m][n][g] + bv;
            }
        }
    }
}

// ---------------------------------------------------------------------------
// aggregation over PADDED CSR with INLINE minimal-exp attention weights.
// f16 ae; int4-vectorized srt_src loads; depth-1 double buffer.
// ---------------------------------------------------------------------------
#define LOADBLK(S_, W_, X_, base_) { \
    int4 sv0 = *(const int4*)(srt_src + (base_)); \
    int4 sv1 = *(const int4*)(srt_src + (base_) + 4); \
    S_[0] = sv0.x; S_[1] = sv0.y; S_[2] = sv0.z; S_[3] = sv0.w; \
    S_[4] = sv1.x; S_[5] = sv1.y; S_[6] = sv1.z; S_[7] = sv1.w; \
    float aev = h2f(ae[(size_t)(base_) * 8 + lane]); \
    int sl = srt_src[(base_) + (lane >> 3)]; \
    float asv = a_src[(size_t)sl * 8 + hw]; \
    float alv = asv + adw + aev; \
    alv = alv > 0.f ? alv : 0.2f * alv; \
    float wvv = __expf(alv); \
    _Pragma("unroll") \
    for (int k = 0; k < 8; ++k) { \
        float ww = __shfl(wvv, (k << 3) | h, 64); \
        W_[k] = ((base_) + k < rend) ? ww : 0.f; } \
    _Pragma("unroll") \
    for (int k = 0; k < 8; ++k) \
        X_[k] = *(const unsigned*)(xs + (size_t)S_[k] * 128 + lane * 2); }

#define CPBLK(W_, X_) { \
    _Pragma("unroll") \
    for (int k = 0; k < 8; ++k) { \
        float wc = W_[k]; unsigned xv = X_[k]; \
        acc0 += wc * lo2f(xv); \
        acc1 += wc * hi2f(xv); \
        denom += wc; } }

__global__ __launch_bounds__(256) void k_agg(const int* __restrict__ rp,
                      const int* __restrict__ deg,
                      const int* __restrict__ srt_src,
                      const u16* __restrict__ ae,
                      const float* __restrict__ a_src, const float* __restrict__ a_dst,
                      const float* __restrict__ se,
                      const u16* __restrict__ xs, const u16* __restrict__ res,
                      const float* __restrict__ bias, const float* __restrict__ gamma,
                      const float* __restrict__ beta, u16* __restrict__ outh) {
    int wv_ = threadIdx.x >> 6, lane = threadIdx.x & 63;
    int i = blockIdx.x * 4 + wv_;
    if (i >= NN) return;
    int h = lane >> 3;                       // own head (features 2lane, 2lane+1)
    int hw = lane & 7;                       // weight-compute head
    int b0 = __builtin_amdgcn_readfirstlane(rp[i]);
    int en = __builtin_amdgcn_readfirstlane(rp[i + 1]);
    int rend = b0 + __builtin_amdgcn_readfirstlane(deg[i]);
    float adw = a_dst[i * 8 + hw];
    float acc0 = 0.f, acc1 = 0.f, denom = 0.f;
    if (b0 < en) {
        int SA[8], SB[8]; float WA[8], WB[8]; unsigned XA[8], XB[8];
        int base = b0;
        LOADBLK(SA, WA, XA, base)
        while (true) {
            LOADBLK(SB, WB, XB, base + 8)
            CPBLK(WA, XA)
            base += 8; if (base >= en) break;
            LOADBLK(SA, WA, XA, base + 8)
            CPBLK(WB, XB)
            base += 8; if (base >= en) break;
        }
    }
    {   // self loop (mean edge-attr folded to se[h])
        float al = a_src[i * 8 + h] + a_dst[i * 8 + h] + se[h];
        al = al > 0.f ? al : 0.2f * al;
        float wc = __expf(al);
        unsigned xv = *(const unsigned*)(xs + (size_t)i * 128 + lane * 2);
        denom += wc;
        acc0 += wc * lo2f(xv);
        acc1 += wc * hi2f(xv);
    }
    float inv = 1.f / (denom + 1e-16f);
    float2 bi = *(const float2*)(bias + lane * 2);
    float v0 = acc0 * inv + bi.x;
    float v1 = acc1 * inv + bi.y;
    v0 = v0 > 0.f ? v0 : (__expf(v0) - 1.f);
    v1 = v1 > 0.f ? v1 : (__expf(v1) - 1.f);
    unsigned rv = *(const unsigned*)(res + (size_t)i * 128 + lane * 2);
    v0 += lo2f(rv);
    v1 += hi2f(rv);
    float s = v0 + v1, q = v0 * v0 + v1 * v1;
    #pragma unroll
    for (int off = 1; off < 64; off <<= 1) { s += __shfl_xor(s, off, 64); q += __shfl_xor(q, off, 64); }
    float mu = s * (1.f / 128.f);
    float var = q * (1.f / 128.f) - mu * mu;
    float r = rsqrtf(var + 1e-5f);
    float2 ga = *(const float2*)(gamma + lane * 2);
    float2 be = *(const float2*)(beta + lane * 2);
    float o0 = (v0 - mu) * r * ga.x + be.x;
    float o1 = (v1 - mu) * r * ga.y + be.y;
    unsigned ov = (unsigned)f2h(o0) | ((unsigned)f2h(o1) << 16);
    *(unsigned*)(outh + (size_t)i * 128 + lane * 2) = ov;
}

// ---------------------------------------------------------------------------
extern "C" void kernel_launch(void* const* d_in, const int* in_sizes, int n_in,
                              void* d_out, int out_size, void* d_ws, size_t ws_size,
                              hipStream_t stream) {
    const float* x        = (const float*)d_in[0];
    const int*   ei       = (const int*)d_in[1];
    const float* enc_w1   = (const float*)d_in[2];
    const float* enc_b1   = (const float*)d_in[3];
    const float* enc_w2   = (const float*)d_in[4];
    const float* enc_b2   = (const float*)d_in[5];
    const float* in_w     = (const float*)d_in[6];
    const float* in_b     = (const float*)d_in[7];
    const float* lin_w1   = (const float*)d_in[8];
    const float* att_src1 = (const float*)d_in[9];
    const float* att_dst1 = (const float*)d_in[10];
    const float* att_edge1= (const float*)d_in[11];
    const float* lin_ew1  = (const float*)d_in[12];
    const float* bias1    = (const float*)d_in[13];
    const float* lin_w2   = (const float*)d_in[14];
    const float* att_src2 = (const float*)d_in[15];
    const float* att_dst2 = (const float*)d_in[16];
    const float* att_edge2= (const float*)d_in[17];
    const float* lin_ew2  = (const float*)d_in[18];
    const float* bias2    = (const float*)d_in[19];
    const float* g1       = (const float*)d_in[20];
    const float* bn1      = (const float*)d_in[21];
    const float* g2       = (const float*)d_in[22];
    const float* bn2      = (const float*)d_in[23];
    const float* jk_w     = (const float*)d_in[24];
    const float* jk_b     = (const float*)d_in[25];
    float* out = (float*)d_out;

    char* wsp = (char*)d_ws;
    size_t off = 0;
    auto alloc = [&](size_t bytes) -> char* {
        char* p = wsp + off;
        off += (bytes + 255) & ~(size_t)255;
        return p;
    };
    u16* x_bf   = (u16*)alloc(sizeof(u16) * (size_t)NN * 128);
    u16* h0b    = (u16*)alloc(sizeof(u16) * (size_t)NN * 128);
    u16* h1b    = (u16*)alloc(sizeof(u16) * (size_t)NN * 128);
    u16* h2b    = (u16*)alloc(sizeof(u16) * (size_t)NN * 128);
    u16* xsb    = (u16*)alloc(sizeof(u16) * (size_t)NN * 128);
    u16* inw_b  = (u16*)alloc(sizeof(u16) * 16384);
    u16* w1_b   = (u16*)alloc(sizeof(u16) * 16384);
    u16* w2_b   = (u16*)alloc(sizeof(u16) * 16384);
    u16* jkw_b  = (u16*)alloc(sizeof(u16) * 49152);
    u16* ae1    = (u16*)alloc(sizeof(u16) * (size_t)EPAD * 8);
    u16* ae2    = (u16*)alloc(sizeof(u16) * (size_t)EPAD * 8);
    float* norms = (float*)alloc(sizeof(float) * NN);
    float* a_src1= (float*)alloc(sizeof(float) * NN * 8);
    float* a_dst1= (float*)alloc(sizeof(float) * NN * 8);
    float* a_src2= (float*)alloc(sizeof(float) * NN * 8);
    float* a_dst2= (float*)alloc(sizeof(float) * NN * 8);
    float* P1    = (float*)alloc(sizeof(float) * 128);
    float* q1    = (float*)alloc(sizeof(float) * 8);
    float* P2    = (float*)alloc(sizeof(float) * 128);
    float* q2    = (float*)alloc(sizeof(float) * 8);
    float* se1   = (float*)alloc(sizeof(float) * 8);
    float* se2   = (float*)alloc(sizeof(float) * 8);
    // zero-init region: deg + sums + done contiguous, single memset
    int* deg     = (int*)alloc(sizeof(int) * NN);
    float* sums  = (float*)alloc(sizeof(float) * 16);
    unsigned* done = (unsigned*)alloc(sizeof(unsigned));
    int* rp      = (int*)alloc(sizeof(int) * (NN + 1));
    int* cursor  = (int*)alloc(sizeof(int) * NN);
    int* bsum    = (int*)alloc(sizeof(int) * NBLK);
    int* srt_src = (int*)alloc(sizeof(int) * EPAD);
    int* srt_dst = (int*)alloc(sizeof(int) * EPAD);
    (void)ws_size; (void)in_sizes; (void)n_in; (void)out_size;
    const int* epad_ptr = rp + NN;

    hipMemsetAsync(deg, 0, (size_t)((char*)rp - (char*)deg), stream);

    // mega prep: node norms/cvt + weight cvt + precompute + degree hist
    k_prep<<<NBP + 48 + 1 + (EE + 255) / 256, 256, 0, stream>>>(
        x, norms, x_bf,
        in_w, inw_b, lin_w1, w1_b, lin_w2, w2_b, jk_w, jkw_b,
        lin_ew1, att_edge1, lin_ew2, att_edge2, enc_w2, enc_b2, P1, q1, P2, q2,
        ei, deg);
    k_scan1<<<NBLK, 256, 0, stream>>>(deg, bsum);
    k_scan2<<<1, 256, 0, stream>>>(bsum, rp);
    k_scan3<<<NBLK, 256, 0, stream>>>(deg, bsum, rp, cursor);
    k_scatter<<<SCB + (NN + 255) / 256, 256, 0, stream>>>(ei, cursor, deg, rp,
                                                          srt_src, srt_dst, ae1, ae2);
    k_encoder<<<(EPAD + 63) / 64, 256, 0, stream>>>(x_bf, srt_src, srt_dst, norms, enc_w1, enc_b1,
                                                    P1, q1, P2, q2, ae1, ae2, epad_ptr);
    k_redsum<<<512, 256, 0, stream>>>(ae1, ae2, sums, done, se1, se2, epad_ptr);

    int gm = (NN + 127) / 128;
    k_mfma_x2<<<gm, 256, 0, stream>>>(x_bf, inw_b, in_b, w1_b, h0b, xsb,
                                      att_src1, att_dst1, a_src1, a_dst1, NN);
    k_agg<<<(NN + 3) / 4, 256, 0, stream>>>(rp, deg, srt_src, ae1, a_src1, a_dst1, se1,
                                            xsb, h0b, bias1, g1, bn1, h1b);
    k_mfma<false, true><<<gm, 256, 0, stream>>>(h1b, w2_b, nullptr, xsb,
                                                att_src2, att_dst2, a_src2, a_dst2, NN);
    k_agg<<<(NN + 3) / 4, 256, 0, stream>>>(rp, deg, srt_src, ae2, a_src2, a_dst2, se2,
                                            xsb, h1b, bias2, g2, bn2, h2b);
    k_mfma_jk<<<gm, 256, 0, stream>>>(h0b, h1b, h2b, jkw_b, jk_b, out, NN);
}

// Round 17
// 307.044 us; speedup vs baseline: 1.0838x; 1.0084x over previous
//
#include <hip/hip_runtime.h>

#define NN 50000
#define EE 600000
#define FF 128
#define HH 8
#define CC 16
#define DD 128
#define EPAD 950272   // >= EE + 7*NN + 24 sentinels
#define NBLK 196      // ceil(NN/256)

typedef unsigned short u16;
typedef _Float16 h2t __attribute__((ext_vector_type(2)));
typedef _Float16 h8 __attribute__((ext_vector_type(8)));
typedef float f4 __attribute__((ext_vector_type(4)));

#if defined(__has_builtin)
#if __has_builtin(__builtin_amdgcn_fdot2)
#define HAS_FDOT2 1
#endif
#endif

static __device__ __forceinline__ float h2f(u16 u) {
    _Float16 h; __builtin_memcpy(&h, &u, 2); return (float)h;
}
static __device__ __forceinline__ u16 f2h(float f) {
    _Float16 h = (_Float16)f; u16 u; __builtin_memcpy(&u, &h, 2); return u;
}
static __device__ __forceinline__ float lo2f(unsigned x) { return h2f((u16)(x & 0xffff)); }
static __device__ __forceinline__ float hi2f(unsigned x) { return h2f((u16)(x >> 16)); }

static __device__ __forceinline__ float dot8(uint4 a, uint4 b, float c) {
#ifdef HAS_FDOT2
    h2t ax[4], bx[4];
    __builtin_memcpy(&ax, &a, 16); __builtin_memcpy(&bx, &b, 16);
    c = __builtin_amdgcn_fdot2(ax[0], bx[0], c, false);
    c = __builtin_amdgcn_fdot2(ax[1], bx[1], c, false);
    c = __builtin_amdgcn_fdot2(ax[2], bx[2], c, false);
    c = __builtin_amdgcn_fdot2(ax[3], bx[3], c, false);
#else
    c += lo2f(a.x) * lo2f(b.x) + hi2f(a.x) * hi2f(b.x)
       + lo2f(a.y) * lo2f(b.y) + hi2f(a.y) * hi2f(b.y)
       + lo2f(a.z) * lo2f(b.z) + hi2f(a.z) * hi2f(b.z)
       + lo2f(a.w) * lo2f(b.w) + hi2f(a.w) * hi2f(b.w);
#endif
    return c;
}
static __device__ __forceinline__ float dot8h(uint4 a, const h2t* pk, float c) {
#ifdef HAS_FDOT2
    h2t ax[4];
    __builtin_memcpy(&ax, &a, 16);
    c = __builtin_amdgcn_fdot2(ax[0], pk[0], c, false);
    c = __builtin_amdgcn_fdot2(ax[1], pk[1], c, false);
    c = __builtin_amdgcn_fdot2(ax[2], pk[2], c, false);
    c = __builtin_amdgcn_fdot2(ax[3], pk[3], c, false);
#else
    c += lo2f(a.x) * (float)pk[0][0] + hi2f(a.x) * (float)pk[0][1]
       + lo2f(a.y) * (float)pk[1][0] + hi2f(a.y) * (float)pk[1][1]
       + lo2f(a.z) * (float)pk[2][0] + hi2f(a.z) * (float)pk[2][1]
       + lo2f(a.w) * (float)pk[3][0] + hi2f(a.w) * (float)pk[3][1];
#endif
    return c;
}

// LDS tile swizzle: tile is [128 rows][128 f16]; 16B-unit index with XOR
static __device__ __forceinline__ int tswz(int row, int u) {
    return (row * 16 + (u ^ (row & 7))) * 8;   // u16 element index
}

// ---------------------------------------------------------------------------
// MEGA prep kernel: node norms + x->f16 | weight cvt | precompute | histogram
// ---------------------------------------------------------------------------
#define NBP 12500
__global__ void k_prep(const float* __restrict__ x, float* __restrict__ norms,
                       u16* __restrict__ xb,
                       const float* __restrict__ s0, u16* __restrict__ d0,
                       const float* __restrict__ s1, u16* __restrict__ d1,
                       const float* __restrict__ s2, u16* __restrict__ d2,
                       const float* __restrict__ s3, u16* __restrict__ d3,
                       const float* __restrict__ lew1, const float* __restrict__ aew1,
                       const float* __restrict__ lew2, const float* __restrict__ aew2,
                       const float* __restrict__ enc_w2, const float* __restrict__ enc_b2,
                       float* __restrict__ P1, float* __restrict__ q1,
                       float* __restrict__ P2, float* __restrict__ q2,
                       const int* __restrict__ ei, int* __restrict__ deg) {
    __shared__ float sM1[64], sM2[64];
    int bb = blockIdx.x;
    int t = threadIdx.x;
    if (bb < NBP) {
        int wid = t >> 6, lane = t & 63;
        int row = bb * 4 + wid;
        float2 v = ((const float2*)(x + (size_t)row * FF))[lane];
        float s = v.x * v.x + v.y * v.y;
        #pragma unroll
        for (int off = 1; off < 64; off <<= 1) s += __shfl_xor(s, off, 64);
        if (lane == 0) norms[row] = s;
        unsigned pk = (unsigned)f2h(v.x) | ((unsigned)f2h(v.y) << 16);
        *(unsigned*)(xb + (size_t)row * FF + lane * 2) = pk;
    } else if (bb < NBP + 48) {
        int b = bb - NBP;
        const float* s; u16* d; int base;
        if (b < 8)       { s = s0; d = d0; base = b * 2048; }
        else if (b < 16) { s = s1; d = d1; base = (b - 8) * 2048; }
        else if (b < 24) { s = s2; d = d2; base = (b - 16) * 2048; }
        else             { s = s3; d = d3; base = (b - 24) * 2048; }
        int i = base + t * 8;
        float4 v0 = *(const float4*)(s + i);
        float4 v1 = *(const float4*)(s + i + 4);
        u16 o[8] = {f2h(v0.x), f2h(v0.y), f2h(v0.z), f2h(v0.w),
                    f2h(v1.x), f2h(v1.y), f2h(v1.z), f2h(v1.w)};
        *(uint4*)(d + i) = *(uint4*)o;
    } else if (bb == NBP + 48) {
        if (t < 128) {
            int kk = (t & 63) >> 3, h = t & 7;
            const float* lew = (t < 64) ? lew1 : lew2;
            const float* ae  = (t < 64) ? aew1 : aew2;
            float s = 0.f;
            for (int c = 0; c < 16; ++c) s += lew[(h * 16 + c) * 8 + kk] * ae[h * 16 + c];
            if (t < 64) sM1[kk * 8 + h] = s; else sM2[kk * 8 + h] = s;
        }
        __syncthreads();
        if (t < 128) {
            int c = t >> 3, h = t & 7;
            float p1 = 0.f, p2 = 0.f;
            for (int k = 0; k < 8; ++k) {
                float w = enc_w2[k * 16 + c];
                p1 += w * sM1[k * 8 + h];
                p2 += w * sM2[k * 8 + h];
            }
            P1[c * 8 + h] = p1;
            P2[c * 8 + h] = p2;
            if (t < 8) {
                float x1 = 0.f, x2 = 0.f;
                for (int k = 0; k < 8; ++k) { float b = enc_b2[k]; x1 += b * sM1[k * 8 + t]; x2 += b * sM2[k * 8 + t]; }
                q1[t] = x1; q2[t] = x2;
            }
        }
    } else {
        int e = (bb - NBP - 49) * 256 + t;
        if (e < EE) atomicAdd(&deg[ei[EE + e]], 1);
    }
}

// ---------------------------------------------------------------------------
// 3-phase multi-block exclusive scan of padded degrees
// ---------------------------------------------------------------------------
__global__ void k_scan1(const int* __restrict__ deg, int* __restrict__ bsum) {
    int t = threadIdx.x, wid = t >> 6, lane = t & 63;
    int i = blockIdx.x * 256 + t;
    int v = (i < NN) ? ((deg[i] + 7) & ~7) : 0;
    #pragma unroll
    for (int off = 1; off < 64; off <<= 1) v += __shfl_xor(v, off, 64);
    __shared__ int ws[4];
    if (lane == 0) ws[wid] = v;
    __syncthreads();
    if (t == 0) bsum[blockIdx.x] = ws[0] + ws[1] + ws[2] + ws[3];
}

__global__ void k_scan2(int* __restrict__ bsum, int* __restrict__ rp) {
    int t = threadIdx.x, wid = t >> 6, lane = t & 63;
    int v = (t < NBLK) ? bsum[t] : 0;
    int sc = v;
    #pragma unroll
    for (int off = 1; off < 64; off <<= 1) { int n = __shfl_up(sc, off, 64); if (lane >= off) sc += n; }
    __shared__ int ws[4], wso[4];
    if (lane == 63) ws[wid] = sc;
    __syncthreads();
    if (t == 0) {
        int c = 0;
        for (int k = 0; k < 4; ++k) { wso[k] = c; c += ws[k]; }
        rp[NN] = c;
    }
    __syncthreads();
    if (t < NBLK) bsum[t] = sc - v + wso[wid];
}

__global__ void k_scan3(const int* __restrict__ deg, const int* __restrict__ bsum,
                        int* __restrict__ rp, int* __restrict__ cursor) {
    int t = threadIdx.x, wid = t >> 6, lane = t & 63;
    int i = blockIdx.x * 256 + t;
    int v = (i < NN) ? ((deg[i] + 7) & ~7) : 0;
    int sc = v;
    #pragma unroll
    for (int off = 1; off < 64; off <<= 1) { int n = __shfl_up(sc, off, 64); if (lane >= off) sc += n; }
    __shared__ int ws[4], wso[4];
    if (lane == 63) ws[wid] = sc;
    __syncthreads();
    if (t == 0) {
        int c = 0;
        for (int k = 0; k < 4; ++k) { wso[k] = c; c += ws[k]; }
    }
    __syncthreads();
    int ex = bsum[blockIdx.x] + wso[wid] + sc - v;
    if (i < NN) { rp[i] = ex; cursor[i] = ex; }
}

// ---------------------------------------------------------------------------
// scatter (real edges) + fill (padding + sentinels + sentinel-ae zero)
// ---------------------------------------------------------------------------
#define SCB 2344   // ceil(EE/256)
__global__ void k_scatter(const int* __restrict__ ei, int* __restrict__ cursor,
                          const int* __restrict__ deg, const int* __restrict__ rp,
                          int* __restrict__ srt_src, int* __restrict__ srt_dst,
                          u16* __restrict__ ae1, u16* __restrict__ ae2) {
    int bb = blockIdx.x;
    if (bb < SCB) {
        int e = bb * 256 + threadIdx.x;
        if (e < EE) {
            int d = ei[EE + e];
            int pos = atomicAdd(&cursor[d], 1);
            srt_src[pos] = ei[e];
            srt_dst[pos] = d;
        }
    } else {
        int i = (bb - SCB) * 256 + threadIdx.x;
        if (i < NN) {
            int start = rp[i] + deg[i], end = rp[i + 1];
            for (int p = start; p < end; ++p) { srt_src[p] = i; srt_dst[p] = -1; }
        }
        if (i == 0) {
            int ep = rp[NN];
            for (int k = 0; k < 24; ++k) { srt_src[ep + k] = 0; srt_dst[ep + k] = -1; }
            for (int k = 0; k < 192; ++k) { ae1[(size_t)ep * 8 + k] = 0; ae2[(size_t)ep * 8 + k] = 0; }
        }
    }
}

// ---------------------------------------------------------------------------
// K2: edge encoder, phase-interleaved: 4 independent dots -> interleaved
// 4-chain shuffle reduce -> 4 LDS hid writes [j][eq][l] -> one wait ->
// 4 projections. Pad edges skip gathers.
// ---------------------------------------------------------------------------
__global__ void k_encoder(const u16* __restrict__ xb,
                          const int* __restrict__ srt_src, const int* __restrict__ srt_dst,
                          const float* __restrict__ norms,
                          const float* __restrict__ enc_w1, const float* __restrict__ enc_b1,
                          const float* __restrict__ P1, const float* __restrict__ q1,
                          const float* __restrict__ P2, const float* __restrict__ q2,
                          u16* __restrict__ ae1out, u16* __restrict__ ae2out,
                          const int* __restrict__ epad) {
    __shared__ __align__(16) u16 hidbuf[4][16][16];
    int t = threadIdx.x, eq = t >> 4, l = t & 15;
    int conv = l >> 3, h = l & 7;
    int EP = *epad;
    float w0 = enc_w1[l * 4 + 0], w1 = enc_w1[l * 4 + 1];
    float w2 = enc_w1[l * 4 + 2], w3 = enc_w1[l * 4 + 3];
    float cA = w0 - 2.f * w1, cB = w1 + w2, cC = w1 + w3, cb = enc_b1[l];
    const float* Ps = conv ? P2 : P1;
    h2t pk[8];
    #pragma unroll
    for (int c = 0; c < 8; ++c)
        pk[c] = (h2t){(_Float16)Ps[(2 * c) * 8 + h], (_Float16)Ps[(2 * c + 1) * 8 + h]};
    float qreg = conv ? q2[h] : q1[h];
    u16* outp = conv ? ae2out : ae1out;
    int e0 = blockIdx.x * 64 + eq;
    int ss[4], dc[4]; bool ok[4], inr[4];
    #pragma unroll
    for (int j = 0; j < 4; ++j) {
        int e = e0 + j * 16;
        inr[j] = e < EP;
        int eidx = inr[j] ? e : 0;
        int d_ = srt_dst[eidx];
        ss[j] = srt_src[eidx];
        ok[j] = inr[j] && (d_ >= 0);
        dc[j] = d_ >= 0 ? d_ : ss[j];
    }
    uint4 av[4], bv[4];
    float ni[4], nj[4];
    #pragma unroll
    for (int j = 0; j < 4; ++j) {
        if (ok[j]) {
            av[j] = *(const uint4*)(xb + (size_t)ss[j] * FF + l * 8);
            bv[j] = *(const uint4*)(xb + (size_t)dc[j] * FF + l * 8);
            ni[j] = norms[ss[j]]; nj[j] = norms[dc[j]];
        } else {
            ni[j] = 0.f; nj[j] = 0.f;
        }
    }
    // phase 1: independent dots
    float dotv[4];
    #pragma unroll
    for (int j = 0; j < 4; ++j) dotv[j] = ok[j] ? dot8(av[j], bv[j], 0.f) : 0.f;
    // phase 2: interleaved 4-chain shuffle reduce
    #pragma unroll
    for (int off = 1; off < 16; off <<= 1) {
        #pragma unroll
        for (int j = 0; j < 4; ++j) dotv[j] += __shfl_xor(dotv[j], off, 64);
    }
    // phase 3: layer-1 + hid writes (per-j LDS rows)
    #pragma unroll
    for (int j = 0; j < 4; ++j) {
        float v = cA * dotv[j] + cB * ni[j] + cC * nj[j] + cb;
        hidbuf[j][eq][l] = f2h(v > 0.f ? v : 0.f);
    }
    // phase 4: projections (one lgkmcnt wait covers all four rows)
    #pragma unroll
    for (int j = 0; j < 4; ++j) {
        if (!inr[j]) continue;
        int e = e0 + j * 16;
        if (!ok[j]) { outp[(size_t)e * 8 + h] = 0; continue; }
        uint4 h0v = *(const uint4*)&hidbuf[j][eq][0];
        uint4 h1v = *(const uint4*)&hidbuf[j][eq][8];
        float a = dot8h(h0v, pk, qreg);
        a = dot8h(h1v, pk + 4, a);
        outp[(size_t)e * 8 + h] = f2h(a);
    }
}

// ---------------------------------------------------------------------------
// K2b: uint4 grid-stride reduction of f16 ae1/ae2 -> sums[16]; last block -> se.
// ---------------------------------------------------------------------------
__global__ void k_redsum(const u16* __restrict__ a1, const u16* __restrict__ a2,
                         float* __restrict__ sums, unsigned* __restrict__ done,
                         float* __restrict__ se1, float* __restrict__ se2,
                         const int* __restrict__ epad) {
    int tid = threadIdx.x;  // 256
    int nck = *epad;        // uint4 chunks (one per edge position)
    int gid = blockIdx.x * 256 + tid;
    int stride = gridDim.x * 256;
    float c1[8] = {}, c2[8] = {};
    for (int i = gid; i < nck; i += stride) {
        uint4 v1 = ((const uint4*)a1)[i];
        uint4 v2 = ((const uint4*)a2)[i];
        c1[0] += lo2f(v1.x); c1[1] += hi2f(v1.x); c1[2] += lo2f(v1.y); c1[3] += hi2f(v1.y);
        c1[4] += lo2f(v1.z); c1[5] += hi2f(v1.z); c1[6] += lo2f(v1.w); c1[7] += hi2f(v1.w);
        c2[0] += lo2f(v2.x); c2[1] += hi2f(v2.x); c2[2] += lo2f(v2.y); c2[3] += hi2f(v2.y);
        c2[4] += lo2f(v2.z); c2[5] += hi2f(v2.z); c2[6] += lo2f(v2.w); c2[7] += hi2f(v2.w);
    }
    #pragma unroll
    for (int off = 1; off < 64; off <<= 1) {
        #pragma unroll
        for (int k = 0; k < 8; ++k) {
            c1[k] += __shfl_xor(c1[k], off, 64);
            c2[k] += __shfl_xor(c2[k], off, 64);
        }
    }
    __shared__ float b1[4][8], b2[4][8];
    int wid = tid >> 6, lane = tid & 63;
    if (lane == 0) {
        #pragma unroll
        for (int k = 0; k < 8; ++k) { b1[wid][k] = c1[k]; b2[wid][k] = c2[k]; }
    }
    __syncthreads();
    if (tid < 8) {
        float t1 = b1[0][tid] + b1[1][tid] + b1[2][tid] + b1[3][tid];
        float t2 = b2[0][tid] + b2[1][tid] + b2[2][tid] + b2[3][tid];
        atomicAdd(&sums[tid], t1);
        atomicAdd(&sums[8 + tid], t2);
    }
    __syncthreads();
    if (tid == 0) {
        __threadfence();
        unsigned old = atomicAdd(done, 1u);
        if (old == (unsigned)gridDim.x - 1u) {
            __threadfence();
            for (int hh = 0; hh < 8; ++hh) {
                float v1 = atomicAdd(&sums[hh], 0.f);
                float v2 = atomicAdd(&sums[8 + hh], 0.f);
                se1[hh] = v1 * (1.f / (float)EE);
                se2[hh] = v2 * (1.f / (float)EE);
            }
        }
    }
}

// ---------------------------------------------------------------------------
// att epilogue: per-row per-head dots with att vectors, 16-lane xor reduce
// ---------------------------------------------------------------------------
static __device__ __forceinline__ void att_epilogue(const f4 (&acc)[2][8],
        const float* __restrict__ att_src, const float* __restrict__ att_dst,
        float* __restrict__ a_src, float* __restrict__ a_dst,
        int r0, int w, int lr, int lk, int nrows) {
    float attS[8], attD[8];
    #pragma unroll
    for (int n = 0; n < 8; ++n) { attS[n] = att_src[n * 16 + lr]; attD[n] = att_dst[n * 16 + lr]; }
    int hh = lr & 7;
    #pragma unroll
    for (int m = 0; m < 2; ++m) {
        #pragma unroll
        for (int g = 0; g < 4; ++g) {
            float sv[8], dv[8];
            #pragma unroll
            for (int n = 0; n < 8; ++n) { float p = acc[m][n][g]; sv[n] = p * attS[n]; dv[n] = p * attD[n]; }
            #pragma unroll
            for (int off = 1; off < 16; off <<= 1) {
                #pragma unroll
                for (int n = 0; n < 8; ++n) {
                    sv[n] += __shfl_xor(sv[n], off, 64);
                    dv[n] += __shfl_xor(dv[n], off, 64);
                }
            }
            float so = lr < 8 ? sv[0] : dv[0];
            #pragma unroll
            for (int n = 1; n < 8; ++n) { float c = lr < 8 ? sv[n] : dv[n]; so = (hh == n) ? c : so; }
            int row = r0 + w * 32 + m * 16 + lk * 4 + g;
            if (row < nrows) {
                float* p = lr < 8 ? a_src : a_dst;
                p[(size_t)row * 8 + hh] = so;
            }
        }
    }
}

// ---------------------------------------------------------------------------
// f16 MFMA GEMM (+optional fused att scores)
// ---------------------------------------------------------------------------
template <bool BIAS, bool ATT>
__global__ __launch_bounds__(256, 2) void k_mfma(const u16* __restrict__ X,
                                                 const u16* __restrict__ W,
                                                 const float* __restrict__ bias,
                                                 u16* __restrict__ out,
                                                 const float* __restrict__ att_src,
                                                 const float* __restrict__ att_dst,
                                                 float* __restrict__ a_src,
                                                 float* __restrict__ a_dst, int nrows) {
    __shared__ __align__(16) u16 tA[128 * 128];
    __shared__ __align__(16) u16 tB[128 * 128];
    int t = threadIdx.x;
    int r0 = blockIdx.x * 128;
    #pragma unroll
    for (int it = 0; it < 8; ++it) {
        int idx = it * 256 + t;
        int r = idx >> 4, u = idx & 15;
        uint4 v = make_uint4(0u, 0u, 0u, 0u);
        if (r0 + r < nrows) v = *(const uint4*)(X + (size_t)(r0 + r) * 128 + u * 8);
        *(uint4*)&tA[tswz(r, u)] = v;
        uint4 wv = *(const uint4*)(W + (size_t)r * 128 + u * 8);
        *(uint4*)&tB[tswz(r, u)] = wv;
    }
    __syncthreads();
    int l = t & 63, w = t >> 6;
    int lr = l & 15, lk = l >> 4;
    f4 acc[2][8];
    #pragma unroll
    for (int m = 0; m < 2; ++m)
        #pragma unroll
        for (int n = 0; n < 8; ++n) acc[m][n] = (f4){0.f, 0.f, 0.f, 0.f};
    #pragma unroll
    for (int s = 0; s < 4; ++s) {
        int u = s * 4 + lk;
        h8 a0 = *(h8*)&tA[tswz(w * 32 + lr, u)];
        h8 a1 = *(h8*)&tA[tswz(w * 32 + 16 + lr, u)];
        #pragma unroll
        for (int n = 0; n < 8; ++n) {
            h8 b = *(h8*)&tB[tswz(n * 16 + lr, u)];
            acc[0][n] = __builtin_amdgcn_mfma_f32_16x16x32_f16(a0, b, acc[0][n], 0, 0, 0);
            acc[1][n] = __builtin_amdgcn_mfma_f32_16x16x32_f16(a1, b, acc[1][n], 0, 0, 0);
        }
    }
    #pragma unroll
    for (int n = 0; n < 8; ++n) {
        int col = n * 16 + lr;
        float bv = BIAS ? bias[col] : 0.f;
        #pragma unroll
        for (int m = 0; m < 2; ++m) {
            #pragma unroll
            for (int g = 0; g < 4; ++g) {
                int row = r0 + w * 32 + m * 16 + lk * 4 + g;
                if (row < nrows) out[(size_t)row * 128 + col] = f2h(acc[m][n][g] + bv);
            }
        }
    }
    if (ATT) att_epilogue(acc, att_src, att_dst, a_src, a_dst, r0, w, lr, lk, nrows);
}

// ---------------------------------------------------------------------------
// fused dual GEMM on shared A-tile: out0 = X@W0^T + b0;  out1 = X@W1^T (+att)
// ---------------------------------------------------------------------------
__global__ __launch_bounds__(256, 2) void k_mfma_x2(const u16* __restrict__ X,
                                                    const u16* __restrict__ W0,
                                                    const float* __restrict__ b0,
                                                    const u16* __restrict__ W1,
                                                    u16* __restrict__ out0,
                                                    u16* __restrict__ out1,
                                                    const float* __restrict__ att_src,
                                                    const float* __restrict__ att_dst,
                                                    float* __restrict__ a_src,
                                                    float* __restrict__ a_dst, int nrows) {
    __shared__ __align__(16) u16 tA[128 * 128];
    __shared__ __align__(16) u16 tB[128 * 128];
    int t = threadIdx.x;
    int r0 = blockIdx.x * 128;
    #pragma unroll
    for (int it = 0; it < 8; ++it) {
        int idx = it * 256 + t;
        int r = idx >> 4, u = idx & 15;
        uint4 v = make_uint4(0u, 0u, 0u, 0u);
        if (r0 + r < nrows) v = *(const uint4*)(X + (size_t)(r0 + r) * 128 + u * 8);
        *(uint4*)&tA[tswz(r, u)] = v;
        uint4 wv = *(const uint4*)(W0 + (size_t)r * 128 + u * 8);
        *(uint4*)&tB[tswz(r, u)] = wv;
    }
    __syncthreads();
    int l = t & 63, w = t >> 6;
    int lr = l & 15, lk = l >> 4;
    f4 acc[2][8];
    #pragma unroll
    for (int m = 0; m < 2; ++m)
        #pragma unroll
        for (int n = 0; n < 8; ++n) acc[m][n] = (f4){0.f, 0.f, 0.f, 0.f};
    #pragma unroll
    for (int s = 0; s < 4; ++s) {
        int u = s * 4 + lk;
        h8 a0 = *(h8*)&tA[tswz(w * 32 + lr, u)];
        h8 a1 = *(h8*)&tA[tswz(w * 32 + 16 + lr, u)];
        #pragma unroll
        for (int n = 0; n < 8; ++n) {
            h8 b = *(h8*)&tB[tswz(n * 16 + lr, u)];
            acc[0][n] = __builtin_amdgcn_mfma_f32_16x16x32_f16(a0, b, acc[0][n], 0, 0, 0);
            acc[1][n] = __builtin_amdgcn_mfma_f32_16x16x32_f16(a1, b, acc[1][n], 0, 0, 0);
        }
    }
    #pragma unroll
    for (int n = 0; n < 8; ++n) {
        int col = n * 16 + lr;
        float bv = b0[col];
        #pragma unroll
        for (int m = 0; m < 2; ++m)
            #pragma unroll
            for (int g = 0; g < 4; ++g) {
                int row = r0 + w * 32 + m * 16 + lk * 4 + g;
                if (row < nrows) out0[(size_t)row * 128 + col] = f2h(acc[m][n][g] + bv);
            }
    }
    __syncthreads();   // all reads of tB done
    #pragma unroll
    for (int it = 0; it < 8; ++it) {
        int idx = it * 256 + t;
        int r = idx >> 4, u = idx & 15;
        uint4 wv = *(const uint4*)(W1 + (size_t)r * 128 + u * 8);
        *(uint4*)&tB[tswz(r, u)] = wv;
    }
    __syncthreads();
    #pragma unroll
    for (int m = 0; m < 2; ++m)
        #pragma unroll
        for (int n = 0; n < 8; ++n) acc[m][n] = (f4){0.f, 0.f, 0.f, 0.f};
    #pragma unroll
    for (int s = 0; s < 4; ++s) {
        int u = s * 4 + lk;
        h8 a0 = *(h8*)&tA[tswz(w * 32 + lr, u)];
        h8 a1 = *(h8*)&tA[tswz(w * 32 + 16 + lr, u)];
        #pragma unroll
        for (int n = 0; n < 8; ++n) {
            h8 b = *(h8*)&tB[tswz(n * 16 + lr, u)];
            acc[0][n] = __builtin_amdgcn_mfma_f32_16x16x32_f16(a0, b, acc[0][n], 0, 0, 0);
            acc[1][n] = __builtin_amdgcn_mfma_f32_16x16x32_f16(a1, b, acc[1][n], 0, 0, 0);
        }
    }
    #pragma unroll
    for (int n = 0; n < 8; ++n) {
        int col = n * 16 + lr;
        #pragma unroll
        for (int m = 0; m < 2; ++m)
            #pragma unroll
            for (int g = 0; g < 4; ++g) {
                int row = r0 + w * 32 + m * 16 + lk * 4 + g;
                if (row < nrows) out1[(size_t)row * 128 + col] = f2h(acc[m][n][g]);
            }
    }
    att_epilogue(acc, att_src, att_dst, a_src, a_dst, r0, w, lr, lk, nrows);
}

// ---------------------------------------------------------------------------
// fused JK MFMA GEMM: out_f32 = [h0 h1 h2]_f16 @ jk_w^T + jk_b (K=384)
// ---------------------------------------------------------------------------
__global__ __launch_bounds__(256, 2) void k_mfma_jk(const u16* __restrict__ h0,
                                                    const u16* __restrict__ h1,
                                                    const u16* __restrict__ h2,
                                                    const u16* __restrict__ W,
                                                    const float* __restrict__ bias,
                                                    float* __restrict__ out, int nrows) {
    __shared__ __align__(16) u16 tA[128 * 128];
    __shared__ __align__(16) u16 tB[128 * 128];
    int t = threadIdx.x;
    int r0 = blockIdx.x * 128;
    int l = t & 63, w = t >> 6;
    int lr = l & 15, lk = l >> 4;
    f4 acc[2][8];
    #pragma unroll
    for (int m = 0; m < 2; ++m)
        #pragma unroll
        for (int n = 0; n < 8; ++n) acc[m][n] = (f4){0.f, 0.f, 0.f, 0.f};
    for (int seg = 0; seg < 3; ++seg) {
        if (seg) __syncthreads();
        const u16* X = seg == 0 ? h0 : (seg == 1 ? h1 : h2);
        #pragma unroll
        for (int it = 0; it < 8; ++it) {
            int idx = it * 256 + t;
            int r = idx >> 4, u = idx & 15;
            uint4 v = make_uint4(0u, 0u, 0u, 0u);
            if (r0 + r < nrows) v = *(const uint4*)(X + (size_t)(r0 + r) * 128 + u * 8);
            *(uint4*)&tA[tswz(r, u)] = v;
            uint4 wv = *(const uint4*)(W + (size_t)r * 384 + seg * 128 + u * 8);
            *(uint4*)&tB[tswz(r, u)] = wv;
        }
        __syncthreads();
        #pragma unroll
        for (int s = 0; s < 4; ++s) {
            int u = s * 4 + lk;
            h8 a0 = *(h8*)&tA[tswz(w * 32 + lr, u)];
            h8 a1 = *(h8*)&tA[tswz(w * 32 + 16 + lr, u)];
            #pragma unroll
            for (int n = 0; n < 8; ++n) {
                h8 b = *(h8*)&tB[tswz(n * 16 + lr, u)];
                acc[0][n] = __builtin_amdgcn_mfma_f32_16x16x32_f16(a0, b, acc[0][n], 0, 0, 0);
                acc[1][n] = __builtin_amdgcn_mfma_f32_16x16x32_f16(a1, b, acc[1][n], 0, 0, 0);
            }
        }
    }
    #pragma unroll
    for (int n = 0; n < 8; ++n) {
        int col = n * 16 + lr;
        float bv = bias[col];
        #pragma unroll
        for (int m = 0; m < 2; ++m) {
            #pragma unroll
            for (int g = 0; g < 4; ++g) {
                int row = r0 + w * 32 + m * 16 + lk * 4 + g;
                if (row < nrows) out[(size_t)row * 128 + col] = acc[m][n][g] + bv;
            }
        }
    }
}

// ---------------------------------------------------------------------------
// aggregation over PADDED CSR with INLINE minimal-exp attention weights.
// f16 ae; int4-vectorized srt_src loads; depth-1 double buffer.
// ---------------------------------------------------------------------------
#define LOADBLK(S_, W_, X_, base_) { \
    int4 sv0 = *(const int4*)(srt_src + (base_)); \
    int4 sv1 = *(const int4*)(srt_src + (base_) + 4); \
    S_[0] = sv0.x; S_[1] = sv0.y; S_[2] = sv0.z; S_[3] = sv0.w; \
    S_[4] = sv1.x; S_[5] = sv1.y; S_[6] = sv1.z; S_[7] = sv1.w; \
    float aev = h2f(ae[(size_t)(base_) * 8 + lane]); \
    int sl = srt_src[(base_) + (lane >> 3)]; \
    float asv = a_src[(size_t)sl * 8 + hw]; \
    float alv = asv + adw + aev; \
    alv = alv > 0.f ? alv : 0.2f * alv; \
    float wvv = __expf(alv); \
    _Pragma("unroll") \
    for (int k = 0; k < 8; ++k) { \
        float ww = __shfl(wvv, (k << 3) | h, 64); \
        W_[k] = ((base_) + k < rend) ? ww : 0.f; } \
    _Pragma("unroll") \
    for (int k = 0; k < 8; ++k) \
        X_[k] = *(const unsigned*)(xs + (size_t)S_[k] * 128 + lane * 2); }

#define CPBLK(W_, X_) { \
    _Pragma("unroll") \
    for (int k = 0; k < 8; ++k) { \
        float wc = W_[k]; unsigned xv = X_[k]; \
        acc0 += wc * lo2f(xv); \
        acc1 += wc * hi2f(xv); \
        denom += wc; } }

__global__ __launch_bounds__(256) void k_agg(const int* __restrict__ rp,
                      const int* __restrict__ deg,
                      const int* __restrict__ srt_src,
                      const u16* __restrict__ ae,
                      const float* __restrict__ a_src, const float* __restrict__ a_dst,
                      const float* __restrict__ se,
                      const u16* __restrict__ xs, const u16* __restrict__ res,
                      const float* __restrict__ bias, const float* __restrict__ gamma,
                      const float* __restrict__ beta, u16* __restrict__ outh) {
    int wv_ = threadIdx.x >> 6, lane = threadIdx.x & 63;
    int i = blockIdx.x * 4 + wv_;
    if (i >= NN) return;
    int h = lane >> 3;                       // own head (features 2lane, 2lane+1)
    int hw = lane & 7;                       // weight-compute head
    int b0 = __builtin_amdgcn_readfirstlane(rp[i]);
    int en = __builtin_amdgcn_readfirstlane(rp[i + 1]);
    int rend = b0 + __builtin_amdgcn_readfirstlane(deg[i]);
    float adw = a_dst[i * 8 + hw];
    float acc0 = 0.f, acc1 = 0.f, denom = 0.f;
    if (b0 < en) {
        int SA[8], SB[8]; float WA[8], WB[8]; unsigned XA[8], XB[8];
        int base = b0;
        LOADBLK(SA, WA, XA, base)
        while (true) {
            LOADBLK(SB, WB, XB, base + 8)
            CPBLK(WA, XA)
            base += 8; if (base >= en) break;
            LOADBLK(SA, WA, XA, base + 8)
            CPBLK(WB, XB)
            base += 8; if (base >= en) break;
        }
    }
    {   // self loop (mean edge-attr folded to se[h])
        float al = a_src[i * 8 + h] + a_dst[i * 8 + h] + se[h];
        al = al > 0.f ? al : 0.2f * al;
        float wc = __expf(al);
        unsigned xv = *(const unsigned*)(xs + (size_t)i * 128 + lane * 2);
        denom += wc;
        acc0 += wc * lo2f(xv);
        acc1 += wc * hi2f(xv);
    }
    float inv = 1.f / (denom + 1e-16f);
    float2 bi = *(const float2*)(bias + lane * 2);
    float v0 = acc0 * inv + bi.x;
    float v1 = acc1 * inv + bi.y;
    v0 = v0 > 0.f ? v0 : (__expf(v0) - 1.f);
    v1 = v1 > 0.f ? v1 : (__expf(v1) - 1.f);
    unsigned rv = *(const unsigned*)(res + (size_t)i * 128 + lane * 2);
    v0 += lo2f(rv);
    v1 += hi2f(rv);
    float s = v0 + v1, q = v0 * v0 + v1 * v1;
    #pragma unroll
    for (int off = 1; off < 64; off <<= 1) { s += __shfl_xor(s, off, 64); q += __shfl_xor(q, off, 64); }
    float mu = s * (1.f / 128.f);
    float var = q * (1.f / 128.f) - mu * mu;
    float r = rsqrtf(var + 1e-5f);
    float2 ga = *(const float2*)(gamma + lane * 2);
    float2 be = *(const float2*)(beta + lane * 2);
    float o0 = (v0 - mu) * r * ga.x + be.x;
    float o1 = (v1 - mu) * r * ga.y + be.y;
    unsigned ov = (unsigned)f2h(o0) | ((unsigned)f2h(o1) << 16);
    *(unsigned*)(outh + (size_t)i * 128 + lane * 2) = ov;
}

// ---------------------------------------------------------------------------
extern "C" void kernel_launch(void* const* d_in, const int* in_sizes, int n_in,
                              void* d_out, int out_size, void* d_ws, size_t ws_size,
                              hipStream_t stream) {
    const float* x        = (const float*)d_in[0];
    const int*   ei       = (const int*)d_in[1];
    const float* enc_w1   = (const float*)d_in[2];
    const float* enc_b1   = (const float*)d_in[3];
    const float* enc_w2   = (const float*)d_in[4];
    const float* enc_b2   = (const float*)d_in[5];
    const float* in_w     = (const float*)d_in[6];
    const float* in_b     = (const float*)d_in[7];
    const float* lin_w1   = (const float*)d_in[8];
    const float* att_src1 = (const float*)d_in[9];
    const float* att_dst1 = (const float*)d_in[10];
    const float* att_edge1= (const float*)d_in[11];
    const float* lin_ew1  = (const float*)d_in[12];
    const float* bias1    = (const float*)d_in[13];
    const float* lin_w2   = (const float*)d_in[14];
    const float* att_src2 = (const float*)d_in[15];
    const float* att_dst2 = (const float*)d_in[16];
    const float* att_edge2= (const float*)d_in[17];
    const float* lin_ew2  = (const float*)d_in[18];
    const float* bias2    = (const float*)d_in[19];
    const float* g1       = (const float*)d_in[20];
    const float* bn1      = (const float*)d_in[21];
    const float* g2       = (const float*)d_in[22];
    const float* bn2      = (const float*)d_in[23];
    const float* jk_w     = (const float*)d_in[24];
    const float* jk_b     = (const float*)d_in[25];
    float* out = (float*)d_out;

    char* wsp = (char*)d_ws;
    size_t off = 0;
    auto alloc = [&](size_t bytes) -> char* {
        char* p = wsp + off;
        off += (bytes + 255) & ~(size_t)255;
        return p;
    };
    u16* x_bf   = (u16*)alloc(sizeof(u16) * (size_t)NN * 128);
    u16* h0b    = (u16*)alloc(sizeof(u16) * (size_t)NN * 128);
    u16* h1b    = (u16*)alloc(sizeof(u16) * (size_t)NN * 128);
    u16* h2b    = (u16*)alloc(sizeof(u16) * (size_t)NN * 128);
    u16* xsb    = (u16*)alloc(sizeof(u16) * (size_t)NN * 128);
    u16* inw_b  = (u16*)alloc(sizeof(u16) * 16384);
    u16* w1_b   = (u16*)alloc(sizeof(u16) * 16384);
    u16* w2_b   = (u16*)alloc(sizeof(u16) * 16384);
    u16* jkw_b  = (u16*)alloc(sizeof(u16) * 49152);
    u16* ae1    = (u16*)alloc(sizeof(u16) * (size_t)EPAD * 8);
    u16* ae2    = (u16*)alloc(sizeof(u16) * (size_t)EPAD * 8);
    float* norms = (float*)alloc(sizeof(float) * NN);
    float* a_src1= (float*)alloc(sizeof(float) * NN * 8);
    float* a_dst1= (float*)alloc(sizeof(float) * NN * 8);
    float* a_src2= (float*)alloc(sizeof(float) * NN * 8);
    float* a_dst2= (float*)alloc(sizeof(float) * NN * 8);
    float* P1    = (float*)alloc(sizeof(float) * 128);
    float* q1    = (float*)alloc(sizeof(float) * 8);
    float* P2    = (float*)alloc(sizeof(float) * 128);
    float* q2    = (float*)alloc(sizeof(float) * 8);
    float* se1   = (float*)alloc(sizeof(float) * 8);
    float* se2   = (float*)alloc(sizeof(float) * 8);
    // zero-init region: deg + sums + done contiguous, single memset
    int* deg     = (int*)alloc(sizeof(int) * NN);
    float* sums  = (float*)alloc(sizeof(float) * 16);
    unsigned* done = (unsigned*)alloc(sizeof(unsigned));
    int* rp      = (int*)alloc(sizeof(int) * (NN + 1));
    int* cursor  = (int*)alloc(sizeof(int) * NN);
    int* bsum    = (int*)alloc(sizeof(int) * NBLK);
    int* srt_src = (int*)alloc(sizeof(int) * EPAD);
    int* srt_dst = (int*)alloc(sizeof(int) * EPAD);
    (void)ws_size; (void)in_sizes; (void)n_in; (void)out_size;
    const int* epad_ptr = rp + NN;

    hipMemsetAsync(deg, 0, (size_t)((char*)rp - (char*)deg), stream);

    // mega prep: node norms/cvt + weight cvt + precompute + degree hist
    k_prep<<<NBP + 48 + 1 + (EE + 255) / 256, 256, 0, stream>>>(
        x, norms, x_bf,
        in_w, inw_b, lin_w1, w1_b, lin_w2, w2_b, jk_w, jkw_b,
        lin_ew1, att_edge1, lin_ew2, att_edge2, enc_w2, enc_b2, P1, q1, P2, q2,
        ei, deg);
    k_scan1<<<NBLK, 256, 0, stream>>>(deg, bsum);
    k_scan2<<<1, 256, 0, stream>>>(bsum, rp);
    k_scan3<<<NBLK, 256, 0, stream>>>(deg, bsum, rp, cursor);
    k_scatter<<<SCB + (NN + 255) / 256, 256, 0, stream>>>(ei, cursor, deg, rp,
                                                          srt_src, srt_dst, ae1, ae2);
    k_encoder<<<(EPAD + 63) / 64, 256, 0, stream>>>(x_bf, srt_src, srt_dst, norms, enc_w1, enc_b1,
                                                    P1, q1, P2, q2, ae1, ae2, epad_ptr);
    k_redsum<<<512, 256, 0, stream>>>(ae1, ae2, sums, done, se1, se2, epad_ptr);

    int gm = (NN + 127) / 128;
    k_mfma_x2<<<gm, 256, 0, stream>>>(x_bf, inw_b, in_b, w1_b, h0b, xsb,
                                      att_src1, att_dst1, a_src1, a_dst1, NN);
    k_agg<<<(NN + 3) / 4, 256, 0, stream>>>(rp, deg, srt_src, ae1, a_src1, a_dst1, se1,
                                            xsb, h0b, bias1, g1, bn1, h1b);
    k_mfma<false, true><<<gm, 256, 0, stream>>>(h1b, w2_b, nullptr, xsb,
                                                att_src2, att_dst2, a_src2, a_dst2, NN);
    k_agg<<<(NN + 3) / 4, 256, 0, stream>>>(rp, deg, srt_src, ae2, a_src2, a_dst2, se2,
                                            xsb, h1b, bias2, g2, bn2, h2b);
    k_mfma_jk<<<gm, 256, 0, stream>>>(h0b, h1b, h2b, jkw_b, jk_b, out, NN);
}